// Round 14
// baseline (458.483 us; speedup 1.0000x reference)
//
#include <hip/hip_runtime.h>
#include <math.h>

// Problem dims
#define TT   48
#define NAA  1024
#define NDD  1024
#define NBB  128
#define NTT  2176   // NAA+NDD+NBB
#define INF  16
#define HH   128
#define HTT  256
#define GG   768    // 3*HTT
#define OUTF 128
#define EAA  8192
#define EAD  8192
#define EDD  8192
#define EAB  2048
#define EDB  2048
#define NEDGE (EAA + EDD + EAD + EAB + EDB)   // 28672
#define NGRP 136    // NTT/16 node groups
#define TCH  8      // GRU chunk length (6 chunks of 8)

typedef short bf16x8 __attribute__((ext_vector_type(8)));
typedef float f32x4  __attribute__((ext_vector_type(4)));

// ---------------- workspace layout (in floats) ----------------
static const size_t SZ_PB   = (size_t)TT * NTT * HH;           // bf16 elem count 13,369,344
static const size_t OFF_PB  = 0;                               // bf16 P
static const size_t OFF_ZB  = OFF_PB + SZ_PB / 2;              // bf16 Z (frag-packed)
static const size_t OFF_H0  = OFF_ZB + SZ_PB / 2;              // bf16 h state
static const size_t OFF_BA  = OFF_H0 + (size_t)NTT * HTT / 2;  // 768 fl
static const size_t OFF_BB  = OFF_BA + GG;                     // 768 fl
static const size_t OFF_WTG = OFF_BB + GG;                     // bf16 packed 7x32x512 = 57,344 fl
static const size_t OFF_BT  = OFF_WTG + 57344;                 // 3x128 fl
static const size_t OFF_WIP = OFF_BT + 384;                    // bf16 Wi frag-packed 192x512 = 49,152 fl
static const size_t OFF_WHP = OFF_WIP + 49152;                 // bf16 Wh frag-packed 384x512 = 98,304 fl
static const size_t OFF_POOL= OFF_WHP + 98304;                 // 1024 fl
static const size_t OFF_PART= OFF_POOL + 1024;                 // 136*256 fl
static const size_t OFF_STATS = OFF_PART + 34816;
static const size_t SZ_GI1  = (size_t)TCH * NGRP * 48 * 256 / 2;  // 6,684,672 fl per GI buffer
static const size_t OFF_GI0 = OFF_STATS + 58400;
static const size_t OFF_GI1 = OFF_GI0 + SZ_GI1;
// total ≈ 27.3M floats ≈ 109.3 MB (≤ 133.5 MB proven in r1-r3)

// stats region word offsets (4B words from OFF_STATS)
enum {
  S_CNT_AA=0, S_CNT_DD=1024, S_CNT_AD=2048, S_CNT_AB=3072, S_CNT_DB=3200,
  S_CUR_AA=3328, S_CUR_DD=4352, S_CUR_AD=5376, S_CUR_AB=6400, S_CUR_DB=6528,
  S_ZERO_END=6656,
  S_OFF_AA=6656, S_OFF_DD=7684, S_OFF_AD=8712, S_OFF_AB=9740, S_OFF_DB=9872,
  S_SRC_AA=10004, S_SRC_DD=18196, S_SRC_AD=26388, S_SRC_AB=34580, S_SRC_DB=36628,
  S_NRM_AA=38676, S_NRM_DD=46868,
  S_DIS_AA=55060, S_DIS_DD=56084, S_INV_AD=57108, S_INV_AB=58132, S_INV_DB=58260,
  S_END=58388
};

// ---------------- bf16 helpers ----------------
__device__ __forceinline__ unsigned short f2b(float x) {
  union { float f; unsigned int u; } v; v.f = x;
  unsigned int r = v.u + 0x7FFFu + ((v.u >> 16) & 1u);
  return (unsigned short)(r >> 16);
}
__device__ __forceinline__ float b2f(unsigned short b) {
  union { unsigned int u; float f; } v; v.u = ((unsigned int)b) << 16;
  return v.f;
}

// ---------------- CSR build (merged) ----------------
__global__ void count_all(const int* __restrict__ aa, const int* __restrict__ dd,
                          const int* __restrict__ ad, const int* __restrict__ ab,
                          const int* __restrict__ db, int* __restrict__ st) {
  int e = blockIdx.x * 256 + threadIdx.x;
  if (e < EAA) atomicAdd(&st[S_CNT_AA + aa[EAA + e]], 1);
  else if (e < EAA + EDD) atomicAdd(&st[S_CNT_DD + dd[EDD + (e - EAA)]], 1);
  else if (e < EAA + EDD + EAD) atomicAdd(&st[S_CNT_AD + ad[EAD + (e - EAA - EDD)]], 1);
  else if (e < EAA + EDD + EAD + EAB) atomicAdd(&st[S_CNT_AB + ab[EAB + (e - EAA - EDD - EAD)]], 1);
  else if (e < NEDGE) atomicAdd(&st[S_CNT_DB + db[EDB + (e - EAA - EDD - EAD - EAB)]], 1);
}

__global__ __launch_bounds__(1024) void scan5(int* __restrict__ st) {
  __shared__ int buf[1024];
  int b = blockIdx.x, i = threadIdx.x;
  int n, coff, ooff, uoff, soff, isGcn;
  switch (b) {
    case 0:  n = 1024; coff = S_CNT_AA; ooff = S_OFF_AA; uoff = S_CUR_AA; soff = S_DIS_AA; isGcn = 1; break;
    case 1:  n = 1024; coff = S_CNT_DD; ooff = S_OFF_DD; uoff = S_CUR_DD; soff = S_DIS_DD; isGcn = 1; break;
    case 2:  n = 1024; coff = S_CNT_AD; ooff = S_OFF_AD; uoff = S_CUR_AD; soff = S_INV_AD; isGcn = 0; break;
    case 3:  n = 128;  coff = S_CNT_AB; ooff = S_OFF_AB; uoff = S_CUR_AB; soff = S_INV_AB; isGcn = 0; break;
    default: n = 128;  coff = S_CNT_DB; ooff = S_OFF_DB; uoff = S_CUR_DB; soff = S_INV_DB; isGcn = 0; break;
  }
  float* stf = (float*)st;
  int c = (i < n) ? st[coff + i] : 0;
  buf[i] = c;
  __syncthreads();
  for (int s = 1; s < 1024; s <<= 1) {
    int tv = (i >= s) ? buf[i - s] : 0;
    __syncthreads();
    buf[i] += tv;
    __syncthreads();
  }
  if (i < n) {
    int excl = buf[i] - c;
    st[ooff + i] = excl;
    st[uoff + i] = excl;
    if (i == n - 1) st[ooff + n] = buf[i];
    if (isGcn) stf[soff + i] = (c > 0) ? (1.0f / sqrtf((float)c)) : 0.0f;
    else       stf[soff + i] = 1.0f / (float)(c > 0 ? c : 1);
  }
}

__global__ void fill_all(const int* __restrict__ aa, const int* __restrict__ dd,
                         const int* __restrict__ ad, const int* __restrict__ ab,
                         const int* __restrict__ db, int* __restrict__ st) {
  float* stf = (float*)st;
  int e = blockIdx.x * 256 + threadIdx.x;
  if (e < EAA) {
    int s = aa[e], d = aa[EAA + e];
    int pos = atomicAdd(&st[S_CUR_AA + d], 1);
    st[S_SRC_AA + pos] = s;
    stf[S_NRM_AA + pos] = stf[S_DIS_AA + s] * stf[S_DIS_AA + d];
  } else if (e < EAA + EDD) {
    int i = e - EAA;
    int s = dd[i], d = dd[EDD + i];
    int pos = atomicAdd(&st[S_CUR_DD + d], 1);
    st[S_SRC_DD + pos] = s;
    stf[S_NRM_DD + pos] = stf[S_DIS_DD + s] * stf[S_DIS_DD + d];
  } else if (e < EAA + EDD + EAD) {
    int i = e - EAA - EDD;
    int s = ad[i], d = ad[EAD + i];
    int pos = atomicAdd(&st[S_CUR_AD + d], 1);
    st[S_SRC_AD + pos] = s;
  } else if (e < EAA + EDD + EAD + EAB) {
    int i = e - EAA - EDD - EAD;
    int s = ab[i], d = ab[EAB + i];
    int pos = atomicAdd(&st[S_CUR_AB + d], 1);
    st[S_SRC_AB + pos] = s;
  } else if (e < NEDGE) {
    int i = e - EAA - EDD - EAD - EAB;
    int s = db[i], d = db[EDB + i];
    int pos = atomicAdd(&st[S_CUR_DB + d], 1);
    st[S_SRC_DB + pos] = s;
  }
}

// ---------------- projection (K=16) -> bf16 P: 64 nodes/block, W staged in LDS ----------------
__global__ __launch_bounds__(256) void proj64(
    const float* __restrict__ xa, const float* __restrict__ xd, const float* __restrict__ xb,
    const float* __restrict__ Wpa, const float* __restrict__ bpa,
    const float* __restrict__ Wpd, const float* __restrict__ bpd,
    const float* __restrict__ Wpb, const float* __restrict__ bpb,
    unsigned short* __restrict__ Pb) {
  int b = blockIdx.x;
  int t = b / 34, rb = b % 34;
  const float *x, *W, *bias;
  int xrow0;
  if (rb < 16)      { x = xa; W = Wpa; bias = bpa; xrow0 = t * 1024 + rb * 64; }
  else if (rb < 32) { x = xd; W = Wpd; bias = bpd; xrow0 = t * 1024 + (rb - 16) * 64; }
  else              { x = xb; W = Wpb; bias = bpb; xrow0 = t * 128  + (rb - 32) * 64; }
  __shared__ float WS[16][132];
  __shared__ float XS[64][17];
  int tid = threadIdx.x;
  for (int i = tid; i < 2048; i += 256) WS[i >> 7][i & 127] = W[i];
  for (int i = tid; i < 1024; i += 256) XS[i >> 4][i & 15] = x[(size_t)xrow0 * 16 + i];
  __syncthreads();
  int c = tid & 127, rh = tid >> 7;
  float bs = bias[c];
  int row0 = rb * 64;
#pragma unroll 4
  for (int rr = 0; rr < 32; ++rr) {
    int r = rr * 2 + rh;
    float acc = bs;
#pragma unroll
    for (int k = 0; k < 16; ++k) acc = fmaf(XS[r][k], WS[k][c], acc);
    Pb[((size_t)t * NTT + row0 + r) * 128 + c] = f2b(acc);
  }
}

// ---------------- merged weight prep: WTgP (packed GNN), WiP, WhP, biases ----------------
__global__ __launch_bounds__(512) void prep_w(
    const float* __restrict__ Wg_aa, const float* __restrict__ Wg_dd,
    const float* __restrict__ Wl_ad, const float* __restrict__ Wr_ad,
    const float* __restrict__ Wl_ab, const float* __restrict__ Wl_db,
    const float* __restrict__ Wr_ab, const float* __restrict__ Wr_db,
    const float* __restrict__ bg_aa, const float* __restrict__ bg_dd,
    const float* __restrict__ bl_ad, const float* __restrict__ bl_ab,
    const float* __restrict__ bl_db,
    const float* __restrict__ Wi, const float* __restrict__ Wh,
    const float* __restrict__ bi, const float* __restrict__ bh,
    unsigned short* __restrict__ WTgP, float* __restrict__ BT,
    unsigned short* __restrict__ WiP, unsigned short* __restrict__ WhP,
    float* __restrict__ BA, float* __restrict__ BB) {
  int b = blockIdx.x, tid = threadIdx.x;
  if (b < 7) {
    const float* Ws[7] = {Wg_aa, Wg_dd, Wl_ad, Wr_ad, Wl_ab, Wl_db, Wr_ab};
    const float* W1 = Ws[b];
    for (int idx = tid; idx < 16384; idx += 512) {
      int f = idx >> 9, L8 = idx & 511;
      int lane = L8 >> 3, j = L8 & 7;
      int n = (f >> 2) * 16 + (lane & 15);
      int k = (f & 3) * 32 + ((lane >> 4) << 3) + j;
      float v = W1[k * 128 + n];
      if (b == 6) v += Wr_db[k * 128 + n];
      WTgP[(size_t)b * 16384 + idx] = f2b(v);
    }
    if (b == 0 && tid < 128) {
      BT[tid]       = bg_aa[tid];
      BT[128 + tid] = bg_dd[tid] + bl_ad[tid];
      BT[256 + tid] = bl_ab[tid] + bl_db[tid];
    }
  } else if (b < 31) {
    int gid = (b - 7) * 512 + tid;
    int f = gid >> 6, L = gid & 63;
    int w = f / 24, rem = f % 24, ct = rem >> 2, kt = rem & 3;
    int p = w * 96 + ct * 16 + (L & 15);
    int triple = p / 48, g = (p % 48) / 16, cc = p % 16;
    int orig = g * 256 + triple * 16 + cc;
    int k0 = kt * 32 + ((L >> 4) << 3);
    unsigned short out[8];
#pragma unroll
    for (int j = 0; j < 8; ++j) out[j] = f2b(Wi[(size_t)(k0 + j) * GG + orig]);
    *(uint4*)(WiP + (size_t)f * 512 + L * 8) = *(const uint4*)out;
  } else if (b < 415) {
    int f = b - 31;
    int tg = f >> 3, kt = f & 7;
    int lane = tid >> 3, j = tid & 7;
    int triple = tg / 3, g = tg % 3, cc = lane & 15;
    int orig = g * 256 + triple * 16 + cc;
    int k = kt * 32 + ((lane >> 4) << 3) + j;
    WhP[(size_t)f * 512 + tid] = f2b(Wh[(size_t)k * GG + orig]);
  } else {
    for (int p = tid; p < 768; p += 512) {
      int triple = p / 48, g = (p % 48) / 16, cc = p % 16;
      int orig = g * 256 + triple * 16 + cc;
      BA[p] = (g < 2) ? (bi[orig] + bh[orig]) : bi[orig];
      BB[p] = bh[orig];
    }
  }
}

// ---------------- fused GNN helpers (512-thread layout, PACKED weights) ----------------
__device__ __forceinline__ void gather_agg(
    const unsigned short* __restrict__ Psrc,
    const int* __restrict__ offs, const int* __restrict__ ssrc,
    const float* __restrict__ snorm, const float* __restrict__ inv,
    int dbase, unsigned short AGG[64][136], int tid) {
  int d_local = tid >> 3;
  int cg = (tid & 7) << 4;        // 16-col chunk
  int d = dbase + d_local;
  int e0 = offs[d], e1 = offs[d + 1];
  float a[16];
#pragma unroll
  for (int j = 0; j < 16; ++j) a[j] = 0.f;
  const unsigned short* pb = Psrc + cg;
  for (int eb = e0; eb < e1; eb += 4) {
    bf16x8 v[4][2];
    float sc[4];
#pragma unroll
    for (int j = 0; j < 4; ++j) {
      int e = eb + j;
      int ec = (e < e1) ? e : (e1 - 1);
      int s = ssrc[ec];
      float scj = snorm ? snorm[ec] : 1.0f;
      if (e >= e1) scj = 0.f;
      sc[j] = scj;
      const unsigned short* pr = pb + (size_t)s * 128;
      v[j][0] = *(const bf16x8*)(pr);
      v[j][1] = *(const bf16x8*)(pr + 8);
    }
#pragma unroll
    for (int j = 0; j < 4; ++j)
#pragma unroll
      for (int c = 0; c < 2; ++c)
#pragma unroll
        for (int i = 0; i < 8; ++i)
          a[c * 8 + i] = fmaf(b2f((unsigned short)v[j][c][i]), sc[j], a[c * 8 + i]);
  }
  float scale = inv ? inv[d] : 1.0f;
#pragma unroll
  for (int j = 0; j < 8; ++j) {
    unsigned int pk = (unsigned int)f2b(a[2 * j] * scale)
                    | ((unsigned int)f2b(a[2 * j + 1] * scale) << 16);
    *(unsigned int*)&AGG[d_local][cg + 2 * j] = pk;
  }
}

// MFMA with PACKED B: frag f = (fh+fi)*4 + ks; load = contiguous 1KB burst
__device__ __forceinline__ void mfma_agg(
    const unsigned short AGG[64][136], const unsigned short* __restrict__ wtp,
    f32x4 acc[4], int wr, int fh, int l15, int lk, int lane) {
#pragma unroll
  for (int ks = 0; ks < 4; ++ks) {
    int k = ks * 32 + lk;
    bf16x8 af = *(const bf16x8*)&AGG[wr + l15][k];
#pragma unroll
    for (int fi = 0; fi < 4; ++fi) {
      bf16x8 bfr = *(const bf16x8*)(wtp + (size_t)(((fh + fi) << 2) + ks) * 512 + lane * 8);
      acc[fi] = __builtin_amdgcn_mfma_f32_16x16x32_bf16(af, bfr, acc[fi], 0, 0, 0);
    }
  }
}

__device__ __forceinline__ void mfma_direct(
    const unsigned short* __restrict__ prow, const unsigned short* __restrict__ wtp,
    f32x4 acc[4], int fh, int l15, int lk, int lane) {
#pragma unroll
  for (int ks = 0; ks < 4; ++ks) {
    int k = ks * 32 + lk;
    bf16x8 af = *(const bf16x8*)(prow + k);
#pragma unroll
    for (int fi = 0; fi < 4; ++fi) {
      bf16x8 bfr = *(const bf16x8*)(wtp + (size_t)(((fh + fi) << 2) + ks) * 512 + lane * 8);
      acc[fi] = __builtin_amdgcn_mfma_f32_16x16x32_bf16(af, bfr, acc[fi], 0, 0, 0);
    }
  }
}

// ---------------- fused GNN: 512 threads, per (frame, 64-row slice) block ----------------
__global__ __launch_bounds__(512) void gnn_fused(
    const unsigned short* __restrict__ Pb, unsigned short* __restrict__ Zb,
    const unsigned short* __restrict__ WTgP, const float* __restrict__ BT,
    const int* __restrict__ st) {
  const float* stf = (const float*)st;
  int L = blockIdx.x;
  int slot = L >> 3;                       // 0..203
  int t = (L & 7) + ((slot / 34) << 3);    // XCD frame affinity
  int rb = slot % 34;
  int row0 = rb * 64;
  int tid = threadIdx.x;
  int w = tid >> 6, lane = tid & 63, l15 = lane & 15, lk = (lane >> 4) * 8;
  int wr = (w >> 1) << 4;                  // wave's 16-row block
  int fh = (w & 1) << 2;                   // wave's f-half (0 or 4)

  __shared__ unsigned short AGG[64][136];

  int typ = (rb < 16) ? 0 : (rb < 32 ? 1 : 2);
  const float* bias = BT + typ * 128;
  f32x4 acc[4];
#pragma unroll
  for (int fi = 0; fi < 4; ++fi) {
    float b = bias[(fh + fi) * 16 + l15];
    f32x4 bv = {b, b, b, b};
    acc[fi] = bv;
  }

  const unsigned short* Pt = Pb + (size_t)t * NTT * 128;
  const unsigned short* prowD = Pt + (size_t)(row0 + wr + l15) * 128;

  if (typ == 0) {
    gather_agg(Pt, st + S_OFF_AA, st + S_SRC_AA, stf + S_NRM_AA, nullptr, row0, AGG, tid);
    __syncthreads();
    mfma_agg(AGG, WTgP + 0 * 16384, acc, wr, fh, l15, lk, lane);
  } else if (typ == 1) {
    int dbase = row0 - 1024;
    gather_agg(Pt + 1024 * 128, st + S_OFF_DD, st + S_SRC_DD, stf + S_NRM_DD, nullptr, dbase, AGG, tid);
    __syncthreads();
    mfma_agg(AGG, WTgP + 1 * 16384, acc, wr, fh, l15, lk, lane);
    __syncthreads();
    gather_agg(Pt, st + S_OFF_AD, st + S_SRC_AD, nullptr, stf + S_INV_AD, dbase, AGG, tid);
    __syncthreads();
    mfma_agg(AGG, WTgP + 2 * 16384, acc, wr, fh, l15, lk, lane);
    mfma_direct(prowD, WTgP + 3 * 16384, acc, fh, l15, lk, lane);
  } else {
    int dbase = row0 - 2048;
    gather_agg(Pt, st + S_OFF_AB, st + S_SRC_AB, nullptr, stf + S_INV_AB, dbase, AGG, tid);
    __syncthreads();
    mfma_agg(AGG, WTgP + 4 * 16384, acc, wr, fh, l15, lk, lane);
    __syncthreads();
    gather_agg(Pt + 1024 * 128, st + S_OFF_DB, st + S_SRC_DB, nullptr, stf + S_INV_DB, dbase, AGG, tid);
    __syncthreads();
    mfma_agg(AGG, WTgP + 5 * 16384, acc, wr, fh, l15, lk, lane);
    mfma_direct(prowD, WTgP + 6 * 16384, acc, fh, l15, lk, lane);
  }

  __syncthreads();
#pragma unroll
  for (int fi = 0; fi < 4; ++fi) {
#pragma unroll
    for (int q = 0; q < 4; ++q) {
      int rl = wr + (lane >> 4) * 4 + q;   // C/D: col=l&15, row=(l>>4)*4+q
      AGG[rl][(fh + fi) * 16 + l15] = f2b(acc[fi][q]);
    }
  }
  __syncthreads();
  // write Z in A-fragment-packed order: [t][grp][kt][lanePos][8]
  unsigned short* ztp = Zb + ((size_t)t * NGRP + (row0 >> 4)) * 4 * 512;
  for (int idx = tid; idx < 1024; idx += 512) {
    int r = idx >> 4, c = (idx & 15) << 3;
    int g = r >> 4;
    int kt = c >> 5;
    int lanePos = ((c >> 3) & 3) * 16 + (r & 15);
    *(uint4*)(ztp + ((size_t)g * 4 + kt) * 512 + lanePos * 8) = *(const uint4*)&AGG[r][c];
  }
}

// ---------------- GI GEMM: LDS-free, high occupancy ----------------
__global__ __launch_bounds__(256, 2) void gi_gemm(
    const unsigned short* __restrict__ Zb,
    const unsigned short* __restrict__ WiP,
    const float* __restrict__ BA,
    unsigned short* __restrict__ GI, int tbase) {
  int bid = blockIdx.x;
  int tloc = bid / 68, pair = bid % 68;
  int t = tbase + tloc;
  int tid = threadIdx.x, w = tid >> 6, lane = tid & 63, l15 = lane & 15;

  bf16x8 a[2][4];
#pragma unroll
  for (int gl = 0; gl < 2; ++gl) {
    const unsigned short* zf = Zb + (((size_t)t * NGRP + pair * 2 + gl) * 4) * 512 + lane * 8;
#pragma unroll
    for (int kt = 0; kt < 4; ++kt) a[gl][kt] = *(const bf16x8*)(zf + kt * 512);
  }

  f32x4 acc[2][4][3];
#pragma unroll
  for (int trl = 0; trl < 4; ++trl)
#pragma unroll
    for (int g = 0; g < 3; ++g) {
      int triple = w * 4 + trl;
      float b = BA[triple * 48 + g * 16 + l15];
      f32x4 bv = {b, b, b, b};
      acc[0][trl][g] = bv;
      acc[1][trl][g] = bv;
    }

#pragma unroll
  for (int trl = 0; trl < 4; ++trl) {
    int triple = w * 4 + trl;
    int wW = triple >> 1, ctb = (triple & 1) * 3;
#pragma unroll
    for (int g = 0; g < 3; ++g) {
      const unsigned short* wf = WiP + ((size_t)((wW * 6 + ctb + g) * 4)) * 512 + lane * 8;
#pragma unroll
      for (int kt = 0; kt < 4; ++kt) {
        bf16x8 b = *(const bf16x8*)(wf + kt * 512);
        acc[0][trl][g] = __builtin_amdgcn_mfma_f32_16x16x32_bf16(a[0][kt], b, acc[0][trl][g], 0, 0, 0);
        acc[1][trl][g] = __builtin_amdgcn_mfma_f32_16x16x32_bf16(a[1][kt], b, acc[1][trl][g], 0, 0, 0);
      }
    }
  }

#pragma unroll
  for (int gl = 0; gl < 2; ++gl) {
    unsigned short* gout = GI + (((size_t)tloc * NGRP + pair * 2 + gl) * 48) * 256;
#pragma unroll
    for (int trl = 0; trl < 4; ++trl)
#pragma unroll
      for (int g = 0; g < 3; ++g) {
        int triple = w * 4 + trl;
        unsigned short us[4];
#pragma unroll
        for (int q = 0; q < 4; ++q) us[q] = f2b(acc[gl][trl][g][q]);
        *(uint2*)(gout + (size_t)(triple * 3 + g) * 256 + lane * 4) = *(const uint2*)us;
      }
  }
}

// ---------------- recurrent GRU chunk (standalone; only these 136 blocks pay the LDS) ----------------
// 16 waves, wave = 1 triple; wreg[3][6] from packed WhP + WL (packed kt 6,7) +
// double-buffered HS (1 barrier/step); GI loads issued before MFMA phase (T14).
__global__ __launch_bounds__(1024, 4) void gru_rec(
    const unsigned short* __restrict__ GIcur,
    const unsigned short* __restrict__ WhP,
    const float* __restrict__ BB,
    unsigned short* __restrict__ Hst, int isFirst) {
  __shared__ unsigned short WL[96 * 512];     // Wh kt 6,7 frags: [tg*2+(kt-6)][lane][8], 96KB
  __shared__ unsigned short HS2[2][16][262];  // double-buffered h state

  const int tid = threadIdx.x;
  const int w = tid >> 6;            // 0..15  (= triple index)
  const int lane = tid & 63;
  const int l15 = lane & 15;
  const int lk = (lane >> 4) << 3;
  const int qrow = (lane >> 4) << 2;
  const int node0 = blockIdx.x * 16;

  // WL load: packed frags tg*8+{6,7} -> WL[tg*2+{0,1}]; fully coalesced, conflict-free
  for (int idx = tid; idx < 96 * 512; idx += 1024) {
    int fr = idx >> 9, e = idx & 511;
    int tg = fr >> 1, kt2 = fr & 1;
    WL[idx] = WhP[(size_t)(tg * 8 + 6 + kt2) * 512 + e];
  }
  if (isFirst) {
    for (int idx = tid; idx < 16 * 262; idx += 1024) ((unsigned short*)HS2[0])[idx] = 0;
  } else {
    for (int idx = tid; idx < 16 * 256; idx += 1024) {
      int r = idx >> 8, c = idx & 255;
      HS2[0][r][c] = Hst[(size_t)(node0 + r) * 256 + c];
    }
  }

  // persistent Wh regs from packed WhP: kt 0..5 (coalesced 1KB bursts)
  bf16x8 wreg[3][6];
#pragma unroll
  for (int g = 0; g < 3; ++g)
#pragma unroll
    for (int kt = 0; kt < 6; ++kt)
      wreg[g][kt] = *(const bf16x8*)(WhP + (size_t)((w * 3 + g) * 8 + kt) * 512 + lane * 8);

  const float bbn = BB[w * 48 + 32 + l15];

  float hold[4];
  if (isFirst) {
#pragma unroll
    for (int q = 0; q < 4; ++q) hold[q] = 0.f;
  } else {
#pragma unroll
    for (int q = 0; q < 4; ++q)
      hold[q] = b2f(Hst[(size_t)(node0 + qrow + q) * 256 + w * 16 + l15]);
  }

  __syncthreads();

  const unsigned short* gblk = GIcur + ((size_t)blockIdx.x * 48 + w * 3) * 256 + lane * 4;
  const size_t tstep = (size_t)NGRP * 48 * 256;

#pragma unroll 1
  for (int t = 0; t < TCH; ++t) {
    int tinvv = 0;
    asm volatile("" : "+s"(tinvv));   // block LICM of t-invariant WL reads

    int rd = t & 1, wb = rd ^ 1;

    // GI loads issued now, consumed after the MFMA phase (latency hidden under MFMAs)
    const unsigned short* gb = gblk + (size_t)t * tstep;
    uint2 gr = *(const uint2*)gb;
    uint2 gz = *(const uint2*)(gb + 256);
    uint2 gn = *(const uint2*)(gb + 512);

    f32x4 accR = {0.f, 0.f, 0.f, 0.f};
    f32x4 accZ = {0.f, 0.f, 0.f, 0.f};
    f32x4 accNh = {0.f, 0.f, 0.f, 0.f};
#pragma unroll
    for (int kt = 0; kt < 8; ++kt) {
      bf16x8 a = *(const bf16x8*)&HS2[rd][l15][kt * 32 + lk];
#pragma unroll
      for (int g = 0; g < 3; ++g) {
        bf16x8 b;
        if (kt < 6) b = wreg[g][kt];
        else        b = *(const bf16x8*)&WL[((w * 3 + g) * 2 + (kt - 6)) * 512 + lane * 8 + tinvv];
        if (g == 0)      accR  = __builtin_amdgcn_mfma_f32_16x16x32_bf16(a, b, accR, 0, 0, 0);
        else if (g == 1) accZ  = __builtin_amdgcn_mfma_f32_16x16x32_bf16(a, b, accZ, 0, 0, 0);
        else             accNh = __builtin_amdgcn_mfma_f32_16x16x32_bf16(a, b, accNh, 0, 0, 0);
      }
    }

    unsigned short grs[4], gzs[4], gns[4];
    *(uint2*)grs = gr; *(uint2*)gzs = gz; *(uint2*)gns = gn;
#pragma unroll
    for (int q = 0; q < 4; ++q) {
      float rr = 1.f / (1.f + __expf(-(accR[q] + b2f(grs[q]))));
      float zz = 1.f / (1.f + __expf(-(accZ[q] + b2f(gzs[q]))));
      float x2 = 2.f * (b2f(gns[q]) + rr * (accNh[q] + bbn));
      float nn = 1.f - 2.f / (__expf(x2) + 1.f);     // tanh
      float hn = (1.f - zz) * nn + zz * hold[q];
      unsigned short hb = f2b(hn);
      hold[q] = b2f(hb);
      HS2[wb][qrow + q][w * 16 + l15] = hb;          // write NEXT buffer
    }
    __syncthreads();   // single barrier per step
  }

  // h -> global
#pragma unroll
  for (int q = 0; q < 4; ++q)
    Hst[(size_t)(node0 + qrow + q) * 256 + w * 16 + l15] = f2b(hold[q]);
}

// ---------------- pooling (two-stage) + final projection ----------------
__global__ __launch_bounds__(256) void pool_part(const unsigned short* __restrict__ Hb,
                                                 float* __restrict__ part) {
  int blk = blockIdx.x;   // 0..135, 16 nodes each
  int j = threadIdx.x;
  int base = blk * 16;
  float s = 0.f;
  for (int r = 0; r < 16; ++r) s += b2f(Hb[(size_t)(base + r) * 256 + j]);
  part[blk * 256 + j] = s;
}

__global__ __launch_bounds__(256) void pool_final(const float* __restrict__ part,
                                                  float* __restrict__ pooled) {
  int typ = blockIdx.x;
  int j = threadIdx.x;
  int b0 = (typ == 0) ? 0 : (typ == 1 ? 64 : 128);
  int b1 = (typ == 2) ? 136 : b0 + 64;
  float s = 0.f;
  for (int b = b0; b < b1; ++b) s += part[b * 256 + j];
  pooled[typ * 256 + j] = s / (float)((typ == 2) ? 128 : 1024);
}

__global__ __launch_bounds__(128) void out_kernel(
    const float* __restrict__ pooled, const float* __restrict__ Wout,
    const float* __restrict__ bout, float* __restrict__ out) {
  int o = threadIdx.x;
  float acc = bout[o];
  for (int g = 0; g < GG; ++g) acc = fmaf(pooled[g], Wout[g * 128 + o], acc);
  out[o] = acc;
}

// ---------------- host launcher ----------------
extern "C" void kernel_launch(void* const* d_in, const int* in_sizes, int n_in,
                              void* d_out, int out_size, void* d_ws, size_t ws_size,
                              hipStream_t stream) {
  const float* xa    = (const float*)d_in[0];
  const float* xd    = (const float*)d_in[1];
  const float* xb    = (const float*)d_in[2];
  const int*   ei_aa = (const int*)d_in[3];
  const int*   ei_ad = (const int*)d_in[4];
  const int*   ei_dd = (const int*)d_in[5];
  const int*   ei_ab = (const int*)d_in[6];
  const int*   ei_db = (const int*)d_in[7];
  const float* Wp_a = (const float*)d_in[8];  const float* bp_a = (const float*)d_in[9];
  const float* Wp_d = (const float*)d_in[10]; const float* bp_d = (const float*)d_in[11];
  const float* Wp_b = (const float*)d_in[12]; const float* bp_b = (const float*)d_in[13];
  const float* Wg_aa = (const float*)d_in[14]; const float* bg_aa = (const float*)d_in[15];
  const float* Wg_dd = (const float*)d_in[16]; const float* bg_dd = (const float*)d_in[17];
  const float* Wl_ad = (const float*)d_in[18]; const float* Wr_ad = (const float*)d_in[19];
  const float* bl_ad = (const float*)d_in[20];
  const float* Wl_ab = (const float*)d_in[21]; const float* Wr_ab = (const float*)d_in[22];
  const float* bl_ab = (const float*)d_in[23];
  const float* Wl_db = (const float*)d_in[24]; const float* Wr_db = (const float*)d_in[25];
  const float* bl_db = (const float*)d_in[26];
  const float* Wi   = (const float*)d_in[27]; const float* Wh   = (const float*)d_in[28];
  const float* bi   = (const float*)d_in[29]; const float* bh   = (const float*)d_in[30];
  const float* Wout = (const float*)d_in[31]; const float* bout = (const float*)d_in[32];

  float* ws   = (float*)d_ws;
  unsigned short* Pb  = (unsigned short*)(ws + OFF_PB);
  unsigned short* Zb  = (unsigned short*)(ws + OFF_ZB);
  unsigned short* Hst = (unsigned short*)(ws + OFF_H0);
  float* BA = ws + OFF_BA;
  float* BB = ws + OFF_BB;
  unsigned short* WTgP = (unsigned short*)(ws + OFF_WTG);
  float* BT = ws + OFF_BT;
  unsigned short* WiP = (unsigned short*)(ws + OFF_WIP);
  unsigned short* WhP = (unsigned short*)(ws + OFF_WHP);
  float* pooled = ws + OFF_POOL;
  float* part   = ws + OFF_PART;
  int*   st  = (int*)(ws + OFF_STATS);
  unsigned short* GI0 = (unsigned short*)(ws + OFF_GI0);
  unsigned short* GI1 = (unsigned short*)(ws + OFF_GI1);

  hipMemsetAsync(st, 0, (size_t)S_ZERO_END * 4, stream);

  // --- CSR build (3 kernels) ---
  count_all<<<NEDGE / 256, 256, 0, stream>>>(ei_aa, ei_dd, ei_ad, ei_ab, ei_db, st);
  scan5<<<5, 1024, 0, stream>>>(st);
  fill_all<<<NEDGE / 256, 256, 0, stream>>>(ei_aa, ei_dd, ei_ad, ei_ab, ei_db, st);

  // --- projections + merged weight prep (packed layouts) ---
  proj64<<<TT * 34, 256, 0, stream>>>(xa, xd, xb, Wp_a, bp_a, Wp_d, bp_d, Wp_b, bp_b, Pb);
  prep_w<<<416, 512, 0, stream>>>(Wg_aa, Wg_dd, Wl_ad, Wr_ad, Wl_ab, Wl_db, Wr_ab, Wr_db,
                                  bg_aa, bg_dd, bl_ad, bl_ab, bl_db,
                                  Wi, Wh, bi, bh, WTgP, BT, WiP, WhP, BA, BB);

  // --- fused GNN: Pb -> Zb (frag-packed, XCD frame affinity, packed weights) ---
  gnn_fused<<<TT * 34, 512, 0, stream>>>(Pb, Zb, WTgP, BT, st);

  // --- GRU: alternating LDS-free GI GEMM and LDS-heavy recurrence (decoupled occupancy) ---
  gi_gemm<<<TCH * 68, 256, 0, stream>>>(Zb, WiP, BA, GI0, 0);
  for (int c = 0; c < 6; ++c) {
    unsigned short* gcur = (c & 1) ? GI1 : GI0;
    unsigned short* gnxt = (c & 1) ? GI0 : GI1;
    gru_rec<<<NGRP, 1024, 0, stream>>>(gcur, WhP, BB, Hst, c == 0);
    if (c < 5)
      gi_gemm<<<TCH * 68, 256, 0, stream>>>(Zb, WiP, BA, gnxt, (c + 1) * TCH);
  }

  // --- pool + output ---
  pool_part<<<NGRP, 256, 0, stream>>>(Hst, part);
  pool_final<<<3, 256, 0, stream>>>(part, pooled);
  out_kernel<<<1, 128, 0, stream>>>(pooled, Wout, bout, (float*)d_out);
}

// Round 15
// 358.791 us; speedup vs baseline: 1.2779x; 1.2779x over previous
//
#include <hip/hip_runtime.h>
#include <math.h>

// Problem dims
#define TT   48
#define NAA  1024
#define NDD  1024
#define NBB  128
#define NTT  2176   // NAA+NDD+NBB
#define INF  16
#define HH   128
#define HTT  256
#define GG   768    // 3*HTT
#define OUTF 128
#define EAA  8192
#define EAD  8192
#define EDD  8192
#define EAB  2048
#define EDB  2048
#define NEDGE (EAA + EDD + EAD + EAB + EDB)   // 28672
#define NGRP 136    // NTT/16 node groups
#define TCH  8      // GRU chunk length (6 chunks of 8)

typedef short bf16x8 __attribute__((ext_vector_type(8)));
typedef float f32x4  __attribute__((ext_vector_type(4)));

// ---------------- workspace layout (in floats) ----------------
static const size_t SZ_PB   = (size_t)TT * NTT * HH;           // bf16 elem count 13,369,344
static const size_t OFF_PB  = 0;                               // bf16 P
static const size_t OFF_ZB  = OFF_PB + SZ_PB / 2;              // bf16 Z (frag-packed)
static const size_t OFF_H0  = OFF_ZB + SZ_PB / 2;              // bf16 h state
static const size_t OFF_BA  = OFF_H0 + (size_t)NTT * HTT / 2;  // 768 fl
static const size_t OFF_BB  = OFF_BA + GG;                     // 768 fl
static const size_t OFF_WTG = OFF_BB + GG;                     // bf16 packed 7x32x512 = 57,344 fl
static const size_t OFF_BT  = OFF_WTG + 57344;                 // 3x128 fl
static const size_t OFF_WIP = OFF_BT + 384;                    // bf16 Wi frag-packed 192x512 = 49,152 fl
static const size_t OFF_WHP = OFF_WIP + 49152;                 // bf16 Wh frag-packed 384x512 = 98,304 fl
static const size_t OFF_POOL= OFF_WHP + 98304;                 // 1024 fl
static const size_t OFF_PART= OFF_POOL + 1024;                 // 136*256 fl
static const size_t OFF_STATS = OFF_PART + 34816;
static const size_t SZ_GI1  = (size_t)TCH * NGRP * 48 * 256 / 2;  // 6,684,672 fl per GI buffer
static const size_t OFF_GI0 = OFF_STATS + 58400;
static const size_t OFF_GI1 = OFF_GI0 + SZ_GI1;
// total ≈ 27.3M floats ≈ 109.3 MB (≤ 133.5 MB proven in r1-r3)

// stats region word offsets (4B words from OFF_STATS)
enum {
  S_CNT_AA=0, S_CNT_DD=1024, S_CNT_AD=2048, S_CNT_AB=3072, S_CNT_DB=3200,
  S_CUR_AA=3328, S_CUR_DD=4352, S_CUR_AD=5376, S_CUR_AB=6400, S_CUR_DB=6528,
  S_ZERO_END=6656,
  S_OFF_AA=6656, S_OFF_DD=7684, S_OFF_AD=8712, S_OFF_AB=9740, S_OFF_DB=9872,
  S_SRC_AA=10004, S_SRC_DD=18196, S_SRC_AD=26388, S_SRC_AB=34580, S_SRC_DB=36628,
  S_NRM_AA=38676, S_NRM_DD=46868,
  S_DIS_AA=55060, S_DIS_DD=56084, S_INV_AD=57108, S_INV_AB=58132, S_INV_DB=58260,
  S_END=58388
};

// ---------------- bf16 helpers ----------------
__device__ __forceinline__ unsigned short f2b(float x) {
  union { float f; unsigned int u; } v; v.f = x;
  unsigned int r = v.u + 0x7FFFu + ((v.u >> 16) & 1u);
  return (unsigned short)(r >> 16);
}
__device__ __forceinline__ float b2f(unsigned short b) {
  union { unsigned int u; float f; } v; v.u = ((unsigned int)b) << 16;
  return v.f;
}

// ---------------- CSR build (merged) ----------------
__global__ void count_all(const int* __restrict__ aa, const int* __restrict__ dd,
                          const int* __restrict__ ad, const int* __restrict__ ab,
                          const int* __restrict__ db, int* __restrict__ st) {
  int e = blockIdx.x * 256 + threadIdx.x;
  if (e < EAA) atomicAdd(&st[S_CNT_AA + aa[EAA + e]], 1);
  else if (e < EAA + EDD) atomicAdd(&st[S_CNT_DD + dd[EDD + (e - EAA)]], 1);
  else if (e < EAA + EDD + EAD) atomicAdd(&st[S_CNT_AD + ad[EAD + (e - EAA - EDD)]], 1);
  else if (e < EAA + EDD + EAD + EAB) atomicAdd(&st[S_CNT_AB + ab[EAB + (e - EAA - EDD - EAD)]], 1);
  else if (e < NEDGE) atomicAdd(&st[S_CNT_DB + db[EDB + (e - EAA - EDD - EAD - EAB)]], 1);
}

__global__ __launch_bounds__(1024) void scan5(int* __restrict__ st) {
  __shared__ int buf[1024];
  int b = blockIdx.x, i = threadIdx.x;
  int n, coff, ooff, uoff, soff, isGcn;
  switch (b) {
    case 0:  n = 1024; coff = S_CNT_AA; ooff = S_OFF_AA; uoff = S_CUR_AA; soff = S_DIS_AA; isGcn = 1; break;
    case 1:  n = 1024; coff = S_CNT_DD; ooff = S_OFF_DD; uoff = S_CUR_DD; soff = S_DIS_DD; isGcn = 1; break;
    case 2:  n = 1024; coff = S_CNT_AD; ooff = S_OFF_AD; uoff = S_CUR_AD; soff = S_INV_AD; isGcn = 0; break;
    case 3:  n = 128;  coff = S_CNT_AB; ooff = S_OFF_AB; uoff = S_CUR_AB; soff = S_INV_AB; isGcn = 0; break;
    default: n = 128;  coff = S_CNT_DB; ooff = S_OFF_DB; uoff = S_CUR_DB; soff = S_INV_DB; isGcn = 0; break;
  }
  float* stf = (float*)st;
  int c = (i < n) ? st[coff + i] : 0;
  buf[i] = c;
  __syncthreads();
  for (int s = 1; s < 1024; s <<= 1) {
    int tv = (i >= s) ? buf[i - s] : 0;
    __syncthreads();
    buf[i] += tv;
    __syncthreads();
  }
  if (i < n) {
    int excl = buf[i] - c;
    st[ooff + i] = excl;
    st[uoff + i] = excl;
    if (i == n - 1) st[ooff + n] = buf[i];
    if (isGcn) stf[soff + i] = (c > 0) ? (1.0f / sqrtf((float)c)) : 0.0f;
    else       stf[soff + i] = 1.0f / (float)(c > 0 ? c : 1);
  }
}

__global__ void fill_all(const int* __restrict__ aa, const int* __restrict__ dd,
                         const int* __restrict__ ad, const int* __restrict__ ab,
                         const int* __restrict__ db, int* __restrict__ st) {
  float* stf = (float*)st;
  int e = blockIdx.x * 256 + threadIdx.x;
  if (e < EAA) {
    int s = aa[e], d = aa[EAA + e];
    int pos = atomicAdd(&st[S_CUR_AA + d], 1);
    st[S_SRC_AA + pos] = s;
    stf[S_NRM_AA + pos] = stf[S_DIS_AA + s] * stf[S_DIS_AA + d];
  } else if (e < EAA + EDD) {
    int i = e - EAA;
    int s = dd[i], d = dd[EDD + i];
    int pos = atomicAdd(&st[S_CUR_DD + d], 1);
    st[S_SRC_DD + pos] = s;
    stf[S_NRM_DD + pos] = stf[S_DIS_DD + s] * stf[S_DIS_DD + d];
  } else if (e < EAA + EDD + EAD) {
    int i = e - EAA - EDD;
    int s = ad[i], d = ad[EAD + i];
    int pos = atomicAdd(&st[S_CUR_AD + d], 1);
    st[S_SRC_AD + pos] = s;
  } else if (e < EAA + EDD + EAD + EAB) {
    int i = e - EAA - EDD - EAD;
    int s = ab[i], d = ab[EAB + i];
    int pos = atomicAdd(&st[S_CUR_AB + d], 1);
    st[S_SRC_AB + pos] = s;
  } else if (e < NEDGE) {
    int i = e - EAA - EDD - EAD - EAB;
    int s = db[i], d = db[EDB + i];
    int pos = atomicAdd(&st[S_CUR_DB + d], 1);
    st[S_SRC_DB + pos] = s;
  }
}

// ---------------- projection (K=16) -> bf16 P: 64 nodes/block, W staged in LDS ----------------
__global__ __launch_bounds__(256) void proj64(
    const float* __restrict__ xa, const float* __restrict__ xd, const float* __restrict__ xb,
    const float* __restrict__ Wpa, const float* __restrict__ bpa,
    const float* __restrict__ Wpd, const float* __restrict__ bpd,
    const float* __restrict__ Wpb, const float* __restrict__ bpb,
    unsigned short* __restrict__ Pb) {
  int b = blockIdx.x;
  int t = b / 34, rb = b % 34;
  const float *x, *W, *bias;
  int xrow0;
  if (rb < 16)      { x = xa; W = Wpa; bias = bpa; xrow0 = t * 1024 + rb * 64; }
  else if (rb < 32) { x = xd; W = Wpd; bias = bpd; xrow0 = t * 1024 + (rb - 16) * 64; }
  else              { x = xb; W = Wpb; bias = bpb; xrow0 = t * 128  + (rb - 32) * 64; }
  __shared__ float WS[16][132];
  __shared__ float XS[64][17];
  int tid = threadIdx.x;
  for (int i = tid; i < 2048; i += 256) WS[i >> 7][i & 127] = W[i];
  for (int i = tid; i < 1024; i += 256) XS[i >> 4][i & 15] = x[(size_t)xrow0 * 16 + i];
  __syncthreads();
  int c = tid & 127, rh = tid >> 7;
  float bs = bias[c];
  int row0 = rb * 64;
#pragma unroll 4
  for (int rr = 0; rr < 32; ++rr) {
    int r = rr * 2 + rh;
    float acc = bs;
#pragma unroll
    for (int k = 0; k < 16; ++k) acc = fmaf(XS[r][k], WS[k][c], acc);
    Pb[((size_t)t * NTT + row0 + r) * 128 + c] = f2b(acc);
  }
}

// ---------------- merged weight prep: WTgP (packed GNN), WiP, WhP, biases ----------------
__global__ __launch_bounds__(512) void prep_w(
    const float* __restrict__ Wg_aa, const float* __restrict__ Wg_dd,
    const float* __restrict__ Wl_ad, const float* __restrict__ Wr_ad,
    const float* __restrict__ Wl_ab, const float* __restrict__ Wl_db,
    const float* __restrict__ Wr_ab, const float* __restrict__ Wr_db,
    const float* __restrict__ bg_aa, const float* __restrict__ bg_dd,
    const float* __restrict__ bl_ad, const float* __restrict__ bl_ab,
    const float* __restrict__ bl_db,
    const float* __restrict__ Wi, const float* __restrict__ Wh,
    const float* __restrict__ bi, const float* __restrict__ bh,
    unsigned short* __restrict__ WTgP, float* __restrict__ BT,
    unsigned short* __restrict__ WiP, unsigned short* __restrict__ WhP,
    float* __restrict__ BA, float* __restrict__ BB) {
  int b = blockIdx.x, tid = threadIdx.x;
  if (b < 7) {
    const float* Ws[7] = {Wg_aa, Wg_dd, Wl_ad, Wr_ad, Wl_ab, Wl_db, Wr_ab};
    const float* W1 = Ws[b];
    for (int idx = tid; idx < 16384; idx += 512) {
      int f = idx >> 9, L8 = idx & 511;
      int lane = L8 >> 3, j = L8 & 7;
      int n = (f >> 2) * 16 + (lane & 15);
      int k = (f & 3) * 32 + ((lane >> 4) << 3) + j;
      float v = W1[k * 128 + n];
      if (b == 6) v += Wr_db[k * 128 + n];
      WTgP[(size_t)b * 16384 + idx] = f2b(v);
    }
    if (b == 0 && tid < 128) {
      BT[tid]       = bg_aa[tid];
      BT[128 + tid] = bg_dd[tid] + bl_ad[tid];
      BT[256 + tid] = bl_ab[tid] + bl_db[tid];
    }
  } else if (b < 31) {
    int gid = (b - 7) * 512 + tid;
    int f = gid >> 6, L = gid & 63;
    int w = f / 24, rem = f % 24, ct = rem >> 2, kt = rem & 3;
    int p = w * 96 + ct * 16 + (L & 15);
    int triple = p / 48, g = (p % 48) / 16, cc = p % 16;
    int orig = g * 256 + triple * 16 + cc;
    int k0 = kt * 32 + ((L >> 4) << 3);
    unsigned short out[8];
#pragma unroll
    for (int j = 0; j < 8; ++j) out[j] = f2b(Wi[(size_t)(k0 + j) * GG + orig]);
    *(uint4*)(WiP + (size_t)f * 512 + L * 8) = *(const uint4*)out;
  } else if (b < 415) {
    int f = b - 31;
    int tg = f >> 3, kt = f & 7;
    int lane = tid >> 3, j = tid & 7;
    int triple = tg / 3, g = tg % 3, cc = lane & 15;
    int orig = g * 256 + triple * 16 + cc;
    int k = kt * 32 + ((lane >> 4) << 3) + j;
    WhP[(size_t)f * 512 + tid] = f2b(Wh[(size_t)k * GG + orig]);
  } else {
    for (int p = tid; p < 768; p += 512) {
      int triple = p / 48, g = (p % 48) / 16, cc = p % 16;
      int orig = g * 256 + triple * 16 + cc;
      BA[p] = (g < 2) ? (bi[orig] + bh[orig]) : bi[orig];
      BB[p] = bh[orig];
    }
  }
}

// ---------------- fused GNN helpers (512-thread layout, PACKED weights) ----------------
__device__ __forceinline__ void gather_agg(
    const unsigned short* __restrict__ Psrc,
    const int* __restrict__ offs, const int* __restrict__ ssrc,
    const float* __restrict__ snorm, const float* __restrict__ inv,
    int dbase, unsigned short AGG[64][136], int tid) {
  int d_local = tid >> 3;
  int cg = (tid & 7) << 4;        // 16-col chunk
  int d = dbase + d_local;
  int e0 = offs[d], e1 = offs[d + 1];
  float a[16];
#pragma unroll
  for (int j = 0; j < 16; ++j) a[j] = 0.f;
  const unsigned short* pb = Psrc + cg;
  for (int eb = e0; eb < e1; eb += 4) {
    bf16x8 v[4][2];
    float sc[4];
#pragma unroll
    for (int j = 0; j < 4; ++j) {
      int e = eb + j;
      int ec = (e < e1) ? e : (e1 - 1);
      int s = ssrc[ec];
      float scj = snorm ? snorm[ec] : 1.0f;
      if (e >= e1) scj = 0.f;
      sc[j] = scj;
      const unsigned short* pr = pb + (size_t)s * 128;
      v[j][0] = *(const bf16x8*)(pr);
      v[j][1] = *(const bf16x8*)(pr + 8);
    }
#pragma unroll
    for (int j = 0; j < 4; ++j)
#pragma unroll
      for (int c = 0; c < 2; ++c)
#pragma unroll
        for (int i = 0; i < 8; ++i)
          a[c * 8 + i] = fmaf(b2f((unsigned short)v[j][c][i]), sc[j], a[c * 8 + i]);
  }
  float scale = inv ? inv[d] : 1.0f;
#pragma unroll
  for (int j = 0; j < 8; ++j) {
    unsigned int pk = (unsigned int)f2b(a[2 * j] * scale)
                    | ((unsigned int)f2b(a[2 * j + 1] * scale) << 16);
    *(unsigned int*)&AGG[d_local][cg + 2 * j] = pk;
  }
}

// MFMA with PACKED B: frag f = (fh+fi)*4 + ks; load = contiguous 1KB burst
__device__ __forceinline__ void mfma_agg(
    const unsigned short AGG[64][136], const unsigned short* __restrict__ wtp,
    f32x4 acc[4], int wr, int fh, int l15, int lk, int lane) {
#pragma unroll
  for (int ks = 0; ks < 4; ++ks) {
    int k = ks * 32 + lk;
    bf16x8 af = *(const bf16x8*)&AGG[wr + l15][k];
#pragma unroll
    for (int fi = 0; fi < 4; ++fi) {
      bf16x8 bfr = *(const bf16x8*)(wtp + (size_t)(((fh + fi) << 2) + ks) * 512 + lane * 8);
      acc[fi] = __builtin_amdgcn_mfma_f32_16x16x32_bf16(af, bfr, acc[fi], 0, 0, 0);
    }
  }
}

__device__ __forceinline__ void mfma_direct(
    const unsigned short* __restrict__ prow, const unsigned short* __restrict__ wtp,
    f32x4 acc[4], int fh, int l15, int lk, int lane) {
#pragma unroll
  for (int ks = 0; ks < 4; ++ks) {
    int k = ks * 32 + lk;
    bf16x8 af = *(const bf16x8*)(prow + k);
#pragma unroll
    for (int fi = 0; fi < 4; ++fi) {
      bf16x8 bfr = *(const bf16x8*)(wtp + (size_t)(((fh + fi) << 2) + ks) * 512 + lane * 8);
      acc[fi] = __builtin_amdgcn_mfma_f32_16x16x32_bf16(af, bfr, acc[fi], 0, 0, 0);
    }
  }
}

// ---------------- fused GNN: 512 threads, per (frame, 64-row slice) block ----------------
__global__ __launch_bounds__(512) void gnn_fused(
    const unsigned short* __restrict__ Pb, unsigned short* __restrict__ Zb,
    const unsigned short* __restrict__ WTgP, const float* __restrict__ BT,
    const int* __restrict__ st) {
  const float* stf = (const float*)st;
  int L = blockIdx.x;
  int slot = L >> 3;                       // 0..203
  int t = (L & 7) + ((slot / 34) << 3);    // XCD frame affinity
  int rb = slot % 34;
  int row0 = rb * 64;
  int tid = threadIdx.x;
  int w = tid >> 6, lane = tid & 63, l15 = lane & 15, lk = (lane >> 4) * 8;
  int wr = (w >> 1) << 4;                  // wave's 16-row block
  int fh = (w & 1) << 2;                   // wave's f-half (0 or 4)

  __shared__ unsigned short AGG[64][136];

  int typ = (rb < 16) ? 0 : (rb < 32 ? 1 : 2);
  const float* bias = BT + typ * 128;
  f32x4 acc[4];
#pragma unroll
  for (int fi = 0; fi < 4; ++fi) {
    float b = bias[(fh + fi) * 16 + l15];
    f32x4 bv = {b, b, b, b};
    acc[fi] = bv;
  }

  const unsigned short* Pt = Pb + (size_t)t * NTT * 128;
  const unsigned short* prowD = Pt + (size_t)(row0 + wr + l15) * 128;

  if (typ == 0) {
    gather_agg(Pt, st + S_OFF_AA, st + S_SRC_AA, stf + S_NRM_AA, nullptr, row0, AGG, tid);
    __syncthreads();
    mfma_agg(AGG, WTgP + 0 * 16384, acc, wr, fh, l15, lk, lane);
  } else if (typ == 1) {
    int dbase = row0 - 1024;
    gather_agg(Pt + 1024 * 128, st + S_OFF_DD, st + S_SRC_DD, stf + S_NRM_DD, nullptr, dbase, AGG, tid);
    __syncthreads();
    mfma_agg(AGG, WTgP + 1 * 16384, acc, wr, fh, l15, lk, lane);
    __syncthreads();
    gather_agg(Pt, st + S_OFF_AD, st + S_SRC_AD, nullptr, stf + S_INV_AD, dbase, AGG, tid);
    __syncthreads();
    mfma_agg(AGG, WTgP + 2 * 16384, acc, wr, fh, l15, lk, lane);
    mfma_direct(prowD, WTgP + 3 * 16384, acc, fh, l15, lk, lane);
  } else {
    int dbase = row0 - 2048;
    gather_agg(Pt, st + S_OFF_AB, st + S_SRC_AB, nullptr, stf + S_INV_AB, dbase, AGG, tid);
    __syncthreads();
    mfma_agg(AGG, WTgP + 4 * 16384, acc, wr, fh, l15, lk, lane);
    __syncthreads();
    gather_agg(Pt + 1024 * 128, st + S_OFF_DB, st + S_SRC_DB, nullptr, stf + S_INV_DB, dbase, AGG, tid);
    __syncthreads();
    mfma_agg(AGG, WTgP + 5 * 16384, acc, wr, fh, l15, lk, lane);
    mfma_direct(prowD, WTgP + 6 * 16384, acc, fh, l15, lk, lane);
  }

  __syncthreads();
#pragma unroll
  for (int fi = 0; fi < 4; ++fi) {
#pragma unroll
    for (int q = 0; q < 4; ++q) {
      int rl = wr + (lane >> 4) * 4 + q;   // C/D: col=l&15, row=(l>>4)*4+q
      AGG[rl][(fh + fi) * 16 + l15] = f2b(acc[fi][q]);
    }
  }
  __syncthreads();
  // write Z in A-fragment-packed order: [t][grp][kt][lanePos][8]
  unsigned short* ztp = Zb + ((size_t)t * NGRP + (row0 >> 4)) * 4 * 512;
  for (int idx = tid; idx < 1024; idx += 512) {
    int r = idx >> 4, c = (idx & 15) << 3;
    int g = r >> 4;
    int kt = c >> 5;
    int lanePos = ((c >> 3) & 3) * 16 + (r & 15);
    *(uint4*)(ztp + ((size_t)g * 4 + kt) * 512 + lanePos * 8) = *(const uint4*)&AGG[r][c];
  }
}

// ---------------- GI GEMM (standalone, chunk 0) ----------------
__global__ __launch_bounds__(256, 2) void gi_gemm(
    const unsigned short* __restrict__ Zb,
    const unsigned short* __restrict__ WiP,
    const float* __restrict__ BA,
    unsigned short* __restrict__ GI, int tbase) {
  int bid = blockIdx.x;
  int tloc = bid / 68, pair = bid % 68;
  int t = tbase + tloc;
  int tid = threadIdx.x, w = tid >> 6, lane = tid & 63, l15 = lane & 15;

  bf16x8 a[2][4];
#pragma unroll
  for (int gl = 0; gl < 2; ++gl) {
    const unsigned short* zf = Zb + (((size_t)t * NGRP + pair * 2 + gl) * 4) * 512 + lane * 8;
#pragma unroll
    for (int kt = 0; kt < 4; ++kt) a[gl][kt] = *(const bf16x8*)(zf + kt * 512);
  }

  f32x4 acc[2][4][3];
#pragma unroll
  for (int trl = 0; trl < 4; ++trl)
#pragma unroll
    for (int g = 0; g < 3; ++g) {
      int triple = w * 4 + trl;
      float b = BA[triple * 48 + g * 16 + l15];
      f32x4 bv = {b, b, b, b};
      acc[0][trl][g] = bv;
      acc[1][trl][g] = bv;
    }

#pragma unroll
  for (int trl = 0; trl < 4; ++trl) {
    int triple = w * 4 + trl;
    int wW = triple >> 1, ctb = (triple & 1) * 3;
#pragma unroll
    for (int g = 0; g < 3; ++g) {
      const unsigned short* wf = WiP + ((size_t)((wW * 6 + ctb + g) * 4)) * 512 + lane * 8;
#pragma unroll
      for (int kt = 0; kt < 4; ++kt) {
        bf16x8 b = *(const bf16x8*)(wf + kt * 512);
        acc[0][trl][g] = __builtin_amdgcn_mfma_f32_16x16x32_bf16(a[0][kt], b, acc[0][trl][g], 0, 0, 0);
        acc[1][trl][g] = __builtin_amdgcn_mfma_f32_16x16x32_bf16(a[1][kt], b, acc[1][trl][g], 0, 0, 0);
      }
    }
  }

#pragma unroll
  for (int gl = 0; gl < 2; ++gl) {
    unsigned short* gout = GI + (((size_t)tloc * NGRP + pair * 2 + gl) * 48) * 256;
#pragma unroll
    for (int trl = 0; trl < 4; ++trl)
#pragma unroll
      for (int g = 0; g < 3; ++g) {
        int triple = w * 4 + trl;
        unsigned short us[4];
#pragma unroll
        for (int q = 0; q < 4; ++q) us[q] = f2b(acc[gl][trl][g][q]);
        *(uint2*)(gout + (size_t)(triple * 3 + g) * 256 + lane * 4) = *(const uint2*)us;
      }
  }
}

// ---------------- combined GRU chunk: rec blocks [0,NGRP) + GI-for-next blocks [NGRP, NGRP+136) ----------------
// rec: 16 waves, wave = 1 triple; wreg[3][6] from packed WhP + WL (packed kt 6,7) +
//      double-buffered HS (1 barrier/step); GI loads issued before MFMA phase (T14).
// gi:  136 consolidated blocks (4 t-slices each) — ~1 scheduling round on the CUs rec leaves free.
__global__ __launch_bounds__(1024, 4) void gru_combo(
    const unsigned short* __restrict__ GIcur, unsigned short* __restrict__ GInext,
    const unsigned short* __restrict__ Zb, const unsigned short* __restrict__ WiP,
    const unsigned short* __restrict__ WhP,
    const float* __restrict__ BA, const float* __restrict__ BB,
    unsigned short* __restrict__ Hst, int isFirst, int tbaseNext) {
  __shared__ unsigned short WL[96 * 512];     // Wh kt 6,7 frags: [tg*2+(kt-6)][lane][8], 96KB
  __shared__ unsigned short HS2[2][16][262];  // double-buffered h state

  const int tid = threadIdx.x;
  const int w = tid >> 6;            // 0..15  (= triple index)
  const int lane = tid & 63;
  const int l15 = lane & 15;
  const int lk = (lane >> 4) << 3;

  if (blockIdx.x >= NGRP) {
    // ---------- GI GEMM for next chunk: 136 blocks x 4 t-slices ----------
    int bid2 = blockIdx.x - NGRP;     // 0..135
    int pair = bid2 % 68, th = bid2 / 68;
#pragma unroll 1
    for (int tl = 0; tl < 4; ++tl) {
      int tloc = th * 4 + tl;
      int t = tbaseNext + tloc;
      bf16x8 a[2][4];
#pragma unroll
      for (int gl = 0; gl < 2; ++gl) {
        const unsigned short* zf = Zb + (((size_t)t * NGRP + pair * 2 + gl) * 4) * 512 + lane * 8;
#pragma unroll
        for (int kt = 0; kt < 4; ++kt) a[gl][kt] = *(const bf16x8*)(zf + kt * 512);
      }
      f32x4 acc[2][3];
#pragma unroll
      for (int g = 0; g < 3; ++g) {
        float b = BA[w * 48 + g * 16 + l15];
        f32x4 bv = {b, b, b, b};
        acc[0][g] = bv;
        acc[1][g] = bv;
      }
      int wW = w >> 1, ctb = (w & 1) * 3;
#pragma unroll
      for (int g = 0; g < 3; ++g) {
        const unsigned short* wf = WiP + ((size_t)((wW * 6 + ctb + g) * 4)) * 512 + lane * 8;
#pragma unroll
        for (int kt = 0; kt < 4; ++kt) {
          bf16x8 b = *(const bf16x8*)(wf + kt * 512);
          acc[0][g] = __builtin_amdgcn_mfma_f32_16x16x32_bf16(a[0][kt], b, acc[0][g], 0, 0, 0);
          acc[1][g] = __builtin_amdgcn_mfma_f32_16x16x32_bf16(a[1][kt], b, acc[1][g], 0, 0, 0);
        }
      }
#pragma unroll
      for (int gl = 0; gl < 2; ++gl) {
        unsigned short* gout = GInext + (((size_t)tloc * NGRP + pair * 2 + gl) * 48) * 256;
#pragma unroll
        for (int g = 0; g < 3; ++g) {
          unsigned short us[4];
#pragma unroll
          for (int q = 0; q < 4; ++q) us[q] = f2b(acc[gl][g][q]);
          *(uint2*)(gout + (size_t)(w * 3 + g) * 256 + lane * 4) = *(const uint2*)us;
        }
      }
    }
    return;
  }

  // ---------- recurrent h-part for current chunk ----------
  const int qrow = (lane >> 4) << 2;
  const int node0 = blockIdx.x * 16;

  // WL load: packed frags tg*8+{6,7} -> WL[tg*2+{0,1}]; fully coalesced, conflict-free
  for (int idx = tid; idx < 96 * 512; idx += 1024) {
    int fr = idx >> 9, e = idx & 511;
    int tg = fr >> 1, kt2 = fr & 1;
    WL[idx] = WhP[(size_t)(tg * 8 + 6 + kt2) * 512 + e];
  }
  if (isFirst) {
    for (int idx = tid; idx < 16 * 262; idx += 1024) ((unsigned short*)HS2[0])[idx] = 0;
  } else {
    for (int idx = tid; idx < 16 * 256; idx += 1024) {
      int r = idx >> 8, c = idx & 255;
      HS2[0][r][c] = Hst[(size_t)(node0 + r) * 256 + c];
    }
  }

  // persistent Wh regs from packed WhP: kt 0..5 (coalesced 1KB bursts)
  bf16x8 wreg[3][6];
#pragma unroll
  for (int g = 0; g < 3; ++g)
#pragma unroll
    for (int kt = 0; kt < 6; ++kt)
      wreg[g][kt] = *(const bf16x8*)(WhP + (size_t)((w * 3 + g) * 8 + kt) * 512 + lane * 8);

  const float bbn = BB[w * 48 + 32 + l15];

  float hold[4];
  if (isFirst) {
#pragma unroll
    for (int q = 0; q < 4; ++q) hold[q] = 0.f;
  } else {
#pragma unroll
    for (int q = 0; q < 4; ++q)
      hold[q] = b2f(Hst[(size_t)(node0 + qrow + q) * 256 + w * 16 + l15]);
  }

  __syncthreads();

  const unsigned short* gblk = GIcur + ((size_t)blockIdx.x * 48 + w * 3) * 256 + lane * 4;
  const size_t tstep = (size_t)NGRP * 48 * 256;

#pragma unroll 1
  for (int t = 0; t < TCH; ++t) {
    int tinvv = 0;
    asm volatile("" : "+s"(tinvv));   // block LICM of t-invariant WL reads

    int rd = t & 1, wb = rd ^ 1;

    // GI loads issued now, consumed after the MFMA phase (latency hidden under MFMAs)
    const unsigned short* gb = gblk + (size_t)t * tstep;
    uint2 gr = *(const uint2*)gb;
    uint2 gz = *(const uint2*)(gb + 256);
    uint2 gn = *(const uint2*)(gb + 512);

    f32x4 accR = {0.f, 0.f, 0.f, 0.f};
    f32x4 accZ = {0.f, 0.f, 0.f, 0.f};
    f32x4 accNh = {0.f, 0.f, 0.f, 0.f};
#pragma unroll
    for (int kt = 0; kt < 8; ++kt) {
      bf16x8 a = *(const bf16x8*)&HS2[rd][l15][kt * 32 + lk];
#pragma unroll
      for (int g = 0; g < 3; ++g) {
        bf16x8 b;
        if (kt < 6) b = wreg[g][kt];
        else        b = *(const bf16x8*)&WL[((w * 3 + g) * 2 + (kt - 6)) * 512 + lane * 8 + tinvv];
        if (g == 0)      accR  = __builtin_amdgcn_mfma_f32_16x16x32_bf16(a, b, accR, 0, 0, 0);
        else if (g == 1) accZ  = __builtin_amdgcn_mfma_f32_16x16x32_bf16(a, b, accZ, 0, 0, 0);
        else             accNh = __builtin_amdgcn_mfma_f32_16x16x32_bf16(a, b, accNh, 0, 0, 0);
      }
    }

    unsigned short grs[4], gzs[4], gns[4];
    *(uint2*)grs = gr; *(uint2*)gzs = gz; *(uint2*)gns = gn;
#pragma unroll
    for (int q = 0; q < 4; ++q) {
      float rr = 1.f / (1.f + __expf(-(accR[q] + b2f(grs[q]))));
      float zz = 1.f / (1.f + __expf(-(accZ[q] + b2f(gzs[q]))));
      float x2 = 2.f * (b2f(gns[q]) + rr * (accNh[q] + bbn));
      float nn = 1.f - 2.f / (__expf(x2) + 1.f);     // tanh
      float hn = (1.f - zz) * nn + zz * hold[q];
      unsigned short hb = f2b(hn);
      hold[q] = b2f(hb);
      HS2[wb][qrow + q][w * 16 + l15] = hb;          // write NEXT buffer
    }
    __syncthreads();   // single barrier per step
  }

  // h -> global
#pragma unroll
  for (int q = 0; q < 4; ++q)
    Hst[(size_t)(node0 + qrow + q) * 256 + w * 16 + l15] = f2b(hold[q]);
}

// ---------------- pooling (two-stage) + final projection ----------------
__global__ __launch_bounds__(256) void pool_part(const unsigned short* __restrict__ Hb,
                                                 float* __restrict__ part) {
  int blk = blockIdx.x;   // 0..135, 16 nodes each
  int j = threadIdx.x;
  int base = blk * 16;
  float s = 0.f;
  for (int r = 0; r < 16; ++r) s += b2f(Hb[(size_t)(base + r) * 256 + j]);
  part[blk * 256 + j] = s;
}

__global__ __launch_bounds__(256) void pool_final(const float* __restrict__ part,
                                                  float* __restrict__ pooled) {
  int typ = blockIdx.x;
  int j = threadIdx.x;
  int b0 = (typ == 0) ? 0 : (typ == 1 ? 64 : 128);
  int b1 = (typ == 2) ? 136 : b0 + 64;
  float s = 0.f;
  for (int b = b0; b < b1; ++b) s += part[b * 256 + j];
  pooled[typ * 256 + j] = s / (float)((typ == 2) ? 128 : 1024);
}

__global__ __launch_bounds__(128) void out_kernel(
    const float* __restrict__ pooled, const float* __restrict__ Wout,
    const float* __restrict__ bout, float* __restrict__ out) {
  int o = threadIdx.x;
  float acc = bout[o];
  for (int g = 0; g < GG; ++g) acc = fmaf(pooled[g], Wout[g * 128 + o], acc);
  out[o] = acc;
}

// ---------------- host launcher ----------------
extern "C" void kernel_launch(void* const* d_in, const int* in_sizes, int n_in,
                              void* d_out, int out_size, void* d_ws, size_t ws_size,
                              hipStream_t stream) {
  const float* xa    = (const float*)d_in[0];
  const float* xd    = (const float*)d_in[1];
  const float* xb    = (const float*)d_in[2];
  const int*   ei_aa = (const int*)d_in[3];
  const int*   ei_ad = (const int*)d_in[4];
  const int*   ei_dd = (const int*)d_in[5];
  const int*   ei_ab = (const int*)d_in[6];
  const int*   ei_db = (const int*)d_in[7];
  const float* Wp_a = (const float*)d_in[8];  const float* bp_a = (const float*)d_in[9];
  const float* Wp_d = (const float*)d_in[10]; const float* bp_d = (const float*)d_in[11];
  const float* Wp_b = (const float*)d_in[12]; const float* bp_b = (const float*)d_in[13];
  const float* Wg_aa = (const float*)d_in[14]; const float* bg_aa = (const float*)d_in[15];
  const float* Wg_dd = (const float*)d_in[16]; const float* bg_dd = (const float*)d_in[17];
  const float* Wl_ad = (const float*)d_in[18]; const float* Wr_ad = (const float*)d_in[19];
  const float* bl_ad = (const float*)d_in[20];
  const float* Wl_ab = (const float*)d_in[21]; const float* Wr_ab = (const float*)d_in[22];
  const float* bl_ab = (const float*)d_in[23];
  const float* Wl_db = (const float*)d_in[24]; const float* Wr_db = (const float*)d_in[25];
  const float* bl_db = (const float*)d_in[26];
  const float* Wi   = (const float*)d_in[27]; const float* Wh   = (const float*)d_in[28];
  const float* bi   = (const float*)d_in[29]; const float* bh   = (const float*)d_in[30];
  const float* Wout = (const float*)d_in[31]; const float* bout = (const float*)d_in[32];

  float* ws   = (float*)d_ws;
  unsigned short* Pb  = (unsigned short*)(ws + OFF_PB);
  unsigned short* Zb  = (unsigned short*)(ws + OFF_ZB);
  unsigned short* Hst = (unsigned short*)(ws + OFF_H0);
  float* BA = ws + OFF_BA;
  float* BB = ws + OFF_BB;
  unsigned short* WTgP = (unsigned short*)(ws + OFF_WTG);
  float* BT = ws + OFF_BT;
  unsigned short* WiP = (unsigned short*)(ws + OFF_WIP);
  unsigned short* WhP = (unsigned short*)(ws + OFF_WHP);
  float* pooled = ws + OFF_POOL;
  float* part   = ws + OFF_PART;
  int*   st  = (int*)(ws + OFF_STATS);
  unsigned short* GI0 = (unsigned short*)(ws + OFF_GI0);
  unsigned short* GI1 = (unsigned short*)(ws + OFF_GI1);

  hipMemsetAsync(st, 0, (size_t)S_ZERO_END * 4, stream);

  // --- CSR build (3 kernels) ---
  count_all<<<NEDGE / 256, 256, 0, stream>>>(ei_aa, ei_dd, ei_ad, ei_ab, ei_db, st);
  scan5<<<5, 1024, 0, stream>>>(st);
  fill_all<<<NEDGE / 256, 256, 0, stream>>>(ei_aa, ei_dd, ei_ad, ei_ab, ei_db, st);

  // --- projections + merged weight prep (packed layouts) ---
  proj64<<<TT * 34, 256, 0, stream>>>(xa, xd, xb, Wp_a, bp_a, Wp_d, bp_d, Wp_b, bp_b, Pb);
  prep_w<<<416, 512, 0, stream>>>(Wg_aa, Wg_dd, Wl_ad, Wr_ad, Wl_ab, Wl_db, Wr_ab, Wr_db,
                                  bg_aa, bg_dd, bl_ad, bl_ab, bl_db,
                                  Wi, Wh, bi, bh, WTgP, BT, WiP, WhP, BA, BB);

  // --- fused GNN: Pb -> Zb (frag-packed, XCD frame affinity, packed weights) ---
  gnn_fused<<<TT * 34, 512, 0, stream>>>(Pb, Zb, WTgP, BT, st);

  // --- GRU: 6 chunks; GI for chunk c+1 overlaps chunk c's recurrence (consolidated GI blocks) ---
  gi_gemm<<<TCH * 68, 256, 0, stream>>>(Zb, WiP, BA, GI0, 0);
  for (int c = 0; c < 6; ++c) {
    unsigned short* gcur = (c & 1) ? GI1 : GI0;
    unsigned short* gnxt = (c & 1) ? GI0 : GI1;
    int grid = NGRP + ((c < 5) ? 136 : 0);
    gru_combo<<<grid, 1024, 0, stream>>>(gcur, gnxt, Zb, WiP, WhP, BA, BB,
                                         Hst, c == 0, (c + 1) * TCH);
  }

  // --- pool + output ---
  pool_part<<<NGRP, 256, 0, stream>>>(Hst, part);
  pool_final<<<3, 256, 0, stream>>>(part, pooled);
  out_kernel<<<1, 128, 0, stream>>>(pooled, Wout, bout, (float*)d_out);
}

// Round 16
// 350.679 us; speedup vs baseline: 1.3074x; 1.0231x over previous
//
#include <hip/hip_runtime.h>
#include <math.h>

// Problem dims
#define TT   48
#define NAA  1024
#define NDD  1024
#define NBB  128
#define NTT  2176   // NAA+NDD+NBB
#define INF  16
#define HH   128
#define HTT  256
#define GG   768    // 3*HTT
#define OUTF 128
#define EAA  8192
#define EAD  8192
#define EDD  8192
#define EAB  2048
#define EDB  2048
#define NEDGE (EAA + EDD + EAD + EAB + EDB)   // 28672
#define NGRP 136    // NTT/16 node groups
#define TCH  8      // GRU chunk length (6 chunks of 8)

typedef short bf16x8 __attribute__((ext_vector_type(8)));
typedef float f32x4  __attribute__((ext_vector_type(4)));

// ---------------- workspace layout (in floats) ----------------
static const size_t SZ_PB   = (size_t)TT * NTT * HH;           // bf16 elem count 13,369,344
static const size_t OFF_PB  = 0;                               // bf16 P
static const size_t OFF_ZB  = OFF_PB + SZ_PB / 2;              // bf16 Z (frag-packed)
static const size_t OFF_H0  = OFF_ZB + SZ_PB / 2;              // bf16 h state
static const size_t OFF_BA  = OFF_H0 + (size_t)NTT * HTT / 2;  // 768 fl
static const size_t OFF_BB  = OFF_BA + GG;                     // 768 fl
static const size_t OFF_WTG = OFF_BB + GG;                     // bf16 packed 7x32x512 = 57,344 fl
static const size_t OFF_BT  = OFF_WTG + 57344;                 // 3x128 fl
static const size_t OFF_WIP = OFF_BT + 384;                    // bf16 Wi frag-packed 192x512 = 49,152 fl
static const size_t OFF_WHP = OFF_WIP + 49152;                 // bf16 Wh frag-packed 384x512 = 98,304 fl
static const size_t OFF_POOL= OFF_WHP + 98304;                 // 1024 fl
static const size_t OFF_PART= OFF_POOL + 1024;                 // 136*256 fl
static const size_t OFF_STATS = OFF_PART + 34816;
static const size_t SZ_GI1  = (size_t)TCH * NGRP * 48 * 256 / 2;  // 6,684,672 fl per GI buffer
static const size_t OFF_GI0 = OFF_STATS + 58400;
static const size_t OFF_GI1 = OFF_GI0 + SZ_GI1;
// total ≈ 27.3M floats ≈ 109.3 MB (≤ 133.5 MB proven in r1-r3)

// stats region word offsets (4B words from OFF_STATS)
enum {
  S_CNT_AA=0, S_CNT_DD=1024, S_CNT_AD=2048, S_CNT_AB=3072, S_CNT_DB=3200,
  S_CUR_AA=3328, S_CUR_DD=4352, S_CUR_AD=5376, S_CUR_AB=6400, S_CUR_DB=6528,
  S_ZERO_END=6656,
  S_OFF_AA=6656, S_OFF_DD=7684, S_OFF_AD=8712, S_OFF_AB=9740, S_OFF_DB=9872,
  S_SRC_AA=10004, S_SRC_DD=18196, S_SRC_AD=26388, S_SRC_AB=34580, S_SRC_DB=36628,
  S_NRM_AA=38676, S_NRM_DD=46868,
  S_DIS_AA=55060, S_DIS_DD=56084, S_INV_AD=57108, S_INV_AB=58132, S_INV_DB=58260,
  S_END=58388
};

// ---------------- bf16 helpers ----------------
__device__ __forceinline__ unsigned short f2b(float x) {
  union { float f; unsigned int u; } v; v.f = x;
  unsigned int r = v.u + 0x7FFFu + ((v.u >> 16) & 1u);
  return (unsigned short)(r >> 16);
}
__device__ __forceinline__ float b2f(unsigned short b) {
  union { unsigned int u; float f; } v; v.u = ((unsigned int)b) << 16;
  return v.f;
}

// ---------------- CSR build (merged) ----------------
__global__ void count_all(const int* __restrict__ aa, const int* __restrict__ dd,
                          const int* __restrict__ ad, const int* __restrict__ ab,
                          const int* __restrict__ db, int* __restrict__ st) {
  int e = blockIdx.x * 256 + threadIdx.x;
  if (e < EAA) atomicAdd(&st[S_CNT_AA + aa[EAA + e]], 1);
  else if (e < EAA + EDD) atomicAdd(&st[S_CNT_DD + dd[EDD + (e - EAA)]], 1);
  else if (e < EAA + EDD + EAD) atomicAdd(&st[S_CNT_AD + ad[EAD + (e - EAA - EDD)]], 1);
  else if (e < EAA + EDD + EAD + EAB) atomicAdd(&st[S_CNT_AB + ab[EAB + (e - EAA - EDD - EAD)]], 1);
  else if (e < NEDGE) atomicAdd(&st[S_CNT_DB + db[EDB + (e - EAA - EDD - EAD - EAB)]], 1);
}

__global__ __launch_bounds__(1024) void scan5(int* __restrict__ st) {
  __shared__ int buf[1024];
  int b = blockIdx.x, i = threadIdx.x;
  int n, coff, ooff, uoff, soff, isGcn;
  switch (b) {
    case 0:  n = 1024; coff = S_CNT_AA; ooff = S_OFF_AA; uoff = S_CUR_AA; soff = S_DIS_AA; isGcn = 1; break;
    case 1:  n = 1024; coff = S_CNT_DD; ooff = S_OFF_DD; uoff = S_CUR_DD; soff = S_DIS_DD; isGcn = 1; break;
    case 2:  n = 1024; coff = S_CNT_AD; ooff = S_OFF_AD; uoff = S_CUR_AD; soff = S_INV_AD; isGcn = 0; break;
    case 3:  n = 128;  coff = S_CNT_AB; ooff = S_OFF_AB; uoff = S_CUR_AB; soff = S_INV_AB; isGcn = 0; break;
    default: n = 128;  coff = S_CNT_DB; ooff = S_OFF_DB; uoff = S_CUR_DB; soff = S_INV_DB; isGcn = 0; break;
  }
  float* stf = (float*)st;
  int c = (i < n) ? st[coff + i] : 0;
  buf[i] = c;
  __syncthreads();
  for (int s = 1; s < 1024; s <<= 1) {
    int tv = (i >= s) ? buf[i - s] : 0;
    __syncthreads();
    buf[i] += tv;
    __syncthreads();
  }
  if (i < n) {
    int excl = buf[i] - c;
    st[ooff + i] = excl;
    st[uoff + i] = excl;
    if (i == n - 1) st[ooff + n] = buf[i];
    if (isGcn) stf[soff + i] = (c > 0) ? (1.0f / sqrtf((float)c)) : 0.0f;
    else       stf[soff + i] = 1.0f / (float)(c > 0 ? c : 1);
  }
}

__global__ void fill_all(const int* __restrict__ aa, const int* __restrict__ dd,
                         const int* __restrict__ ad, const int* __restrict__ ab,
                         const int* __restrict__ db, int* __restrict__ st) {
  float* stf = (float*)st;
  int e = blockIdx.x * 256 + threadIdx.x;
  if (e < EAA) {
    int s = aa[e], d = aa[EAA + e];
    int pos = atomicAdd(&st[S_CUR_AA + d], 1);
    st[S_SRC_AA + pos] = s;
    stf[S_NRM_AA + pos] = stf[S_DIS_AA + s] * stf[S_DIS_AA + d];
  } else if (e < EAA + EDD) {
    int i = e - EAA;
    int s = dd[i], d = dd[EDD + i];
    int pos = atomicAdd(&st[S_CUR_DD + d], 1);
    st[S_SRC_DD + pos] = s;
    stf[S_NRM_DD + pos] = stf[S_DIS_DD + s] * stf[S_DIS_DD + d];
  } else if (e < EAA + EDD + EAD) {
    int i = e - EAA - EDD;
    int s = ad[i], d = ad[EAD + i];
    int pos = atomicAdd(&st[S_CUR_AD + d], 1);
    st[S_SRC_AD + pos] = s;
  } else if (e < EAA + EDD + EAD + EAB) {
    int i = e - EAA - EDD - EAD;
    int s = ab[i], d = ab[EAB + i];
    int pos = atomicAdd(&st[S_CUR_AB + d], 1);
    st[S_SRC_AB + pos] = s;
  } else if (e < NEDGE) {
    int i = e - EAA - EDD - EAD - EAB;
    int s = db[i], d = db[EDB + i];
    int pos = atomicAdd(&st[S_CUR_DB + d], 1);
    st[S_SRC_DB + pos] = s;
  }
}

// ---------------- projection (K=16) -> bf16 P: 64 nodes/block, W staged in LDS ----------------
__global__ __launch_bounds__(256) void proj64(
    const float* __restrict__ xa, const float* __restrict__ xd, const float* __restrict__ xb,
    const float* __restrict__ Wpa, const float* __restrict__ bpa,
    const float* __restrict__ Wpd, const float* __restrict__ bpd,
    const float* __restrict__ Wpb, const float* __restrict__ bpb,
    unsigned short* __restrict__ Pb) {
  int b = blockIdx.x;
  int t = b / 34, rb = b % 34;
  const float *x, *W, *bias;
  int xrow0;
  if (rb < 16)      { x = xa; W = Wpa; bias = bpa; xrow0 = t * 1024 + rb * 64; }
  else if (rb < 32) { x = xd; W = Wpd; bias = bpd; xrow0 = t * 1024 + (rb - 16) * 64; }
  else              { x = xb; W = Wpb; bias = bpb; xrow0 = t * 128  + (rb - 32) * 64; }
  __shared__ float WS[16][132];
  __shared__ float XS[64][17];
  int tid = threadIdx.x;
  for (int i = tid; i < 2048; i += 256) WS[i >> 7][i & 127] = W[i];
  for (int i = tid; i < 1024; i += 256) XS[i >> 4][i & 15] = x[(size_t)xrow0 * 16 + i];
  __syncthreads();
  int c = tid & 127, rh = tid >> 7;
  float bs = bias[c];
  int row0 = rb * 64;
#pragma unroll 4
  for (int rr = 0; rr < 32; ++rr) {
    int r = rr * 2 + rh;
    float acc = bs;
#pragma unroll
    for (int k = 0; k < 16; ++k) acc = fmaf(XS[r][k], WS[k][c], acc);
    Pb[((size_t)t * NTT + row0 + r) * 128 + c] = f2b(acc);
  }
}

// ---------------- merged weight prep: WTgP (packed GNN), WiP, WhP, biases ----------------
__global__ __launch_bounds__(512) void prep_w(
    const float* __restrict__ Wg_aa, const float* __restrict__ Wg_dd,
    const float* __restrict__ Wl_ad, const float* __restrict__ Wr_ad,
    const float* __restrict__ Wl_ab, const float* __restrict__ Wl_db,
    const float* __restrict__ Wr_ab, const float* __restrict__ Wr_db,
    const float* __restrict__ bg_aa, const float* __restrict__ bg_dd,
    const float* __restrict__ bl_ad, const float* __restrict__ bl_ab,
    const float* __restrict__ bl_db,
    const float* __restrict__ Wi, const float* __restrict__ Wh,
    const float* __restrict__ bi, const float* __restrict__ bh,
    unsigned short* __restrict__ WTgP, float* __restrict__ BT,
    unsigned short* __restrict__ WiP, unsigned short* __restrict__ WhP,
    float* __restrict__ BA, float* __restrict__ BB) {
  int b = blockIdx.x, tid = threadIdx.x;
  if (b < 7) {
    const float* Ws[7] = {Wg_aa, Wg_dd, Wl_ad, Wr_ad, Wl_ab, Wl_db, Wr_ab};
    const float* W1 = Ws[b];
    for (int idx = tid; idx < 16384; idx += 512) {
      int f = idx >> 9, L8 = idx & 511;
      int lane = L8 >> 3, j = L8 & 7;
      int n = (f >> 2) * 16 + (lane & 15);
      int k = (f & 3) * 32 + ((lane >> 4) << 3) + j;
      float v = W1[k * 128 + n];
      if (b == 6) v += Wr_db[k * 128 + n];
      WTgP[(size_t)b * 16384 + idx] = f2b(v);
    }
    if (b == 0 && tid < 128) {
      BT[tid]       = bg_aa[tid];
      BT[128 + tid] = bg_dd[tid] + bl_ad[tid];
      BT[256 + tid] = bl_ab[tid] + bl_db[tid];
    }
  } else if (b < 31) {
    int gid = (b - 7) * 512 + tid;
    int f = gid >> 6, L = gid & 63;
    int w = f / 24, rem = f % 24, ct = rem >> 2, kt = rem & 3;
    int p = w * 96 + ct * 16 + (L & 15);
    int triple = p / 48, g = (p % 48) / 16, cc = p % 16;
    int orig = g * 256 + triple * 16 + cc;
    int k0 = kt * 32 + ((L >> 4) << 3);
    unsigned short out[8];
#pragma unroll
    for (int j = 0; j < 8; ++j) out[j] = f2b(Wi[(size_t)(k0 + j) * GG + orig]);
    *(uint4*)(WiP + (size_t)f * 512 + L * 8) = *(const uint4*)out;
  } else if (b < 415) {
    int f = b - 31;
    int tg = f >> 3, kt = f & 7;
    int lane = tid >> 3, j = tid & 7;
    int triple = tg / 3, g = tg % 3, cc = lane & 15;
    int orig = g * 256 + triple * 16 + cc;
    int k = kt * 32 + ((lane >> 4) << 3) + j;
    WhP[(size_t)f * 512 + tid] = f2b(Wh[(size_t)k * GG + orig]);
  } else {
    for (int p = tid; p < 768; p += 512) {
      int triple = p / 48, g = (p % 48) / 16, cc = p % 16;
      int orig = g * 256 + triple * 16 + cc;
      BA[p] = (g < 2) ? (bi[orig] + bh[orig]) : bi[orig];
      BB[p] = bh[orig];
    }
  }
}

// ---------------- fused GNN helpers (512-thread layout, PACKED weights) ----------------
__device__ __forceinline__ void gather_agg(
    const unsigned short* __restrict__ Psrc,
    const int* __restrict__ offs, const int* __restrict__ ssrc,
    const float* __restrict__ snorm, const float* __restrict__ inv,
    int dbase, unsigned short AGG[64][136], int tid) {
  int d_local = tid >> 3;
  int cg = (tid & 7) << 4;        // 16-col chunk
  int d = dbase + d_local;
  int e0 = offs[d], e1 = offs[d + 1];
  float a[16];
#pragma unroll
  for (int j = 0; j < 16; ++j) a[j] = 0.f;
  const unsigned short* pb = Psrc + cg;
  for (int eb = e0; eb < e1; eb += 4) {
    bf16x8 v[4][2];
    float sc[4];
#pragma unroll
    for (int j = 0; j < 4; ++j) {
      int e = eb + j;
      int ec = (e < e1) ? e : (e1 - 1);
      int s = ssrc[ec];
      float scj = snorm ? snorm[ec] : 1.0f;
      if (e >= e1) scj = 0.f;
      sc[j] = scj;
      const unsigned short* pr = pb + (size_t)s * 128;
      v[j][0] = *(const bf16x8*)(pr);
      v[j][1] = *(const bf16x8*)(pr + 8);
    }
#pragma unroll
    for (int j = 0; j < 4; ++j)
#pragma unroll
      for (int c = 0; c < 2; ++c)
#pragma unroll
        for (int i = 0; i < 8; ++i)
          a[c * 8 + i] = fmaf(b2f((unsigned short)v[j][c][i]), sc[j], a[c * 8 + i]);
  }
  float scale = inv ? inv[d] : 1.0f;
#pragma unroll
  for (int j = 0; j < 8; ++j) {
    unsigned int pk = (unsigned int)f2b(a[2 * j] * scale)
                    | ((unsigned int)f2b(a[2 * j + 1] * scale) << 16);
    *(unsigned int*)&AGG[d_local][cg + 2 * j] = pk;
  }
}

// MFMA with PACKED B: frag f = (fh+fi)*4 + ks; load = contiguous 1KB burst
__device__ __forceinline__ void mfma_agg(
    const unsigned short AGG[64][136], const unsigned short* __restrict__ wtp,
    f32x4 acc[4], int wr, int fh, int l15, int lk, int lane) {
#pragma unroll
  for (int ks = 0; ks < 4; ++ks) {
    int k = ks * 32 + lk;
    bf16x8 af = *(const bf16x8*)&AGG[wr + l15][k];
#pragma unroll
    for (int fi = 0; fi < 4; ++fi) {
      bf16x8 bfr = *(const bf16x8*)(wtp + (size_t)(((fh + fi) << 2) + ks) * 512 + lane * 8);
      acc[fi] = __builtin_amdgcn_mfma_f32_16x16x32_bf16(af, bfr, acc[fi], 0, 0, 0);
    }
  }
}

__device__ __forceinline__ void mfma_direct(
    const unsigned short* __restrict__ prow, const unsigned short* __restrict__ wtp,
    f32x4 acc[4], int fh, int l15, int lk, int lane) {
#pragma unroll
  for (int ks = 0; ks < 4; ++ks) {
    int k = ks * 32 + lk;
    bf16x8 af = *(const bf16x8*)(prow + k);
#pragma unroll
    for (int fi = 0; fi < 4; ++fi) {
      bf16x8 bfr = *(const bf16x8*)(wtp + (size_t)(((fh + fi) << 2) + ks) * 512 + lane * 8);
      acc[fi] = __builtin_amdgcn_mfma_f32_16x16x32_bf16(af, bfr, acc[fi], 0, 0, 0);
    }
  }
}

// ---------------- fused GNN: 512 threads, per (frame, 64-row slice) block ----------------
__global__ __launch_bounds__(512) void gnn_fused(
    const unsigned short* __restrict__ Pb, unsigned short* __restrict__ Zb,
    const unsigned short* __restrict__ WTgP, const float* __restrict__ BT,
    const int* __restrict__ st) {
  const float* stf = (const float*)st;
  int L = blockIdx.x;
  int slot = L >> 3;                       // 0..203
  int t = (L & 7) + ((slot / 34) << 3);    // XCD frame affinity
  int rb = slot % 34;
  int row0 = rb * 64;
  int tid = threadIdx.x;
  int w = tid >> 6, lane = tid & 63, l15 = lane & 15, lk = (lane >> 4) * 8;
  int wr = (w >> 1) << 4;                  // wave's 16-row block
  int fh = (w & 1) << 2;                   // wave's f-half (0 or 4)

  __shared__ unsigned short AGG[64][136];

  int typ = (rb < 16) ? 0 : (rb < 32 ? 1 : 2);
  const float* bias = BT + typ * 128;
  f32x4 acc[4];
#pragma unroll
  for (int fi = 0; fi < 4; ++fi) {
    float b = bias[(fh + fi) * 16 + l15];
    f32x4 bv = {b, b, b, b};
    acc[fi] = bv;
  }

  const unsigned short* Pt = Pb + (size_t)t * NTT * 128;
  const unsigned short* prowD = Pt + (size_t)(row0 + wr + l15) * 128;

  if (typ == 0) {
    gather_agg(Pt, st + S_OFF_AA, st + S_SRC_AA, stf + S_NRM_AA, nullptr, row0, AGG, tid);
    __syncthreads();
    mfma_agg(AGG, WTgP + 0 * 16384, acc, wr, fh, l15, lk, lane);
  } else if (typ == 1) {
    int dbase = row0 - 1024;
    gather_agg(Pt + 1024 * 128, st + S_OFF_DD, st + S_SRC_DD, stf + S_NRM_DD, nullptr, dbase, AGG, tid);
    __syncthreads();
    mfma_agg(AGG, WTgP + 1 * 16384, acc, wr, fh, l15, lk, lane);
    __syncthreads();
    gather_agg(Pt, st + S_OFF_AD, st + S_SRC_AD, nullptr, stf + S_INV_AD, dbase, AGG, tid);
    __syncthreads();
    mfma_agg(AGG, WTgP + 2 * 16384, acc, wr, fh, l15, lk, lane);
    mfma_direct(prowD, WTgP + 3 * 16384, acc, fh, l15, lk, lane);
  } else {
    int dbase = row0 - 2048;
    gather_agg(Pt, st + S_OFF_AB, st + S_SRC_AB, nullptr, stf + S_INV_AB, dbase, AGG, tid);
    __syncthreads();
    mfma_agg(AGG, WTgP + 4 * 16384, acc, wr, fh, l15, lk, lane);
    __syncthreads();
    gather_agg(Pt + 1024 * 128, st + S_OFF_DB, st + S_SRC_DB, nullptr, stf + S_INV_DB, dbase, AGG, tid);
    __syncthreads();
    mfma_agg(AGG, WTgP + 5 * 16384, acc, wr, fh, l15, lk, lane);
    mfma_direct(prowD, WTgP + 6 * 16384, acc, fh, l15, lk, lane);
  }

  __syncthreads();
#pragma unroll
  for (int fi = 0; fi < 4; ++fi) {
#pragma unroll
    for (int q = 0; q < 4; ++q) {
      int rl = wr + (lane >> 4) * 4 + q;   // C/D: col=l&15, row=(l>>4)*4+q
      AGG[rl][(fh + fi) * 16 + l15] = f2b(acc[fi][q]);
    }
  }
  __syncthreads();
  // write Z in A-fragment-packed order: [t][grp][kt][lanePos][8]
  unsigned short* ztp = Zb + ((size_t)t * NGRP + (row0 >> 4)) * 4 * 512;
  for (int idx = tid; idx < 1024; idx += 512) {
    int r = idx >> 4, c = (idx & 15) << 3;
    int g = r >> 4;
    int kt = c >> 5;
    int lanePos = ((c >> 3) & 3) * 16 + (r & 15);
    *(uint4*)(ztp + ((size_t)g * 4 + kt) * 512 + lanePos * 8) = *(const uint4*)&AGG[r][c];
  }
}

// ---------------- GI GEMM (standalone, chunk 0) ----------------
__global__ __launch_bounds__(256, 2) void gi_gemm(
    const unsigned short* __restrict__ Zb,
    const unsigned short* __restrict__ WiP,
    const float* __restrict__ BA,
    unsigned short* __restrict__ GI, int tbase) {
  int bid = blockIdx.x;
  int tloc = bid / 68, pair = bid % 68;
  int t = tbase + tloc;
  int tid = threadIdx.x, w = tid >> 6, lane = tid & 63, l15 = lane & 15;

  bf16x8 a[2][4];
#pragma unroll
  for (int gl = 0; gl < 2; ++gl) {
    const unsigned short* zf = Zb + (((size_t)t * NGRP + pair * 2 + gl) * 4) * 512 + lane * 8;
#pragma unroll
    for (int kt = 0; kt < 4; ++kt) a[gl][kt] = *(const bf16x8*)(zf + kt * 512);
  }

  f32x4 acc[2][4][3];
#pragma unroll
  for (int trl = 0; trl < 4; ++trl)
#pragma unroll
    for (int g = 0; g < 3; ++g) {
      int triple = w * 4 + trl;
      float b = BA[triple * 48 + g * 16 + l15];
      f32x4 bv = {b, b, b, b};
      acc[0][trl][g] = bv;
      acc[1][trl][g] = bv;
    }

#pragma unroll
  for (int trl = 0; trl < 4; ++trl) {
    int triple = w * 4 + trl;
    int wW = triple >> 1, ctb = (triple & 1) * 3;
#pragma unroll
    for (int g = 0; g < 3; ++g) {
      const unsigned short* wf = WiP + ((size_t)((wW * 6 + ctb + g) * 4)) * 512 + lane * 8;
#pragma unroll
      for (int kt = 0; kt < 4; ++kt) {
        bf16x8 b = *(const bf16x8*)(wf + kt * 512);
        acc[0][trl][g] = __builtin_amdgcn_mfma_f32_16x16x32_bf16(a[0][kt], b, acc[0][trl][g], 0, 0, 0);
        acc[1][trl][g] = __builtin_amdgcn_mfma_f32_16x16x32_bf16(a[1][kt], b, acc[1][trl][g], 0, 0, 0);
      }
    }
  }

#pragma unroll
  for (int gl = 0; gl < 2; ++gl) {
    unsigned short* gout = GI + (((size_t)tloc * NGRP + pair * 2 + gl) * 48) * 256;
#pragma unroll
    for (int trl = 0; trl < 4; ++trl)
#pragma unroll
      for (int g = 0; g < 3; ++g) {
        int triple = w * 4 + trl;
        unsigned short us[4];
#pragma unroll
        for (int q = 0; q < 4; ++q) us[q] = f2b(acc[gl][trl][g][q]);
        *(uint2*)(gout + (size_t)(triple * 3 + g) * 256 + lane * 4) = *(const uint2*)us;
      }
  }
}

// ---------------- recurrent step macro (HS2 read buffer RD, write buffer WB) ----------------
#define REC_STEP(GR, GZ, GN, RD, WB, TINV)                                            \
  do {                                                                                \
    f32x4 accR = {0.f, 0.f, 0.f, 0.f};                                                \
    f32x4 accZ = {0.f, 0.f, 0.f, 0.f};                                                \
    f32x4 accNh = {0.f, 0.f, 0.f, 0.f};                                               \
    _Pragma("unroll")                                                                 \
    for (int kt = 0; kt < 8; ++kt) {                                                  \
      bf16x8 a = *(const bf16x8*)&HS2[RD][l15][kt * 32 + lk];                         \
      _Pragma("unroll")                                                               \
      for (int g = 0; g < 3; ++g) {                                                   \
        bf16x8 b;                                                                     \
        if (kt < 6) b = wreg[g][kt];                                                  \
        else b = *(const bf16x8*)&WL[((w * 3 + g) * 2 + (kt - 6)) * 512 +             \
                                     lane * 8 + (TINV)];                              \
        if (g == 0)                                                                   \
          accR = __builtin_amdgcn_mfma_f32_16x16x32_bf16(a, b, accR, 0, 0, 0);        \
        else if (g == 1)                                                              \
          accZ = __builtin_amdgcn_mfma_f32_16x16x32_bf16(a, b, accZ, 0, 0, 0);        \
        else                                                                          \
          accNh = __builtin_amdgcn_mfma_f32_16x16x32_bf16(a, b, accNh, 0, 0, 0);      \
      }                                                                               \
    }                                                                                 \
    unsigned short grs[4], gzs[4], gns[4];                                            \
    *(uint2*)grs = GR; *(uint2*)gzs = GZ; *(uint2*)gns = GN;                          \
    _Pragma("unroll")                                                                 \
    for (int q = 0; q < 4; ++q) {                                                     \
      float rr = 1.f / (1.f + __expf(-(accR[q] + b2f(grs[q]))));                      \
      float zz = 1.f / (1.f + __expf(-(accZ[q] + b2f(gzs[q]))));                      \
      float x2 = 2.f * (b2f(gns[q]) + rr * (accNh[q] + bbn));                         \
      float nn = 1.f - 2.f / (__expf(x2) + 1.f);                                      \
      float hn = (1.f - zz) * nn + zz * hold[q];                                      \
      unsigned short hb = f2b(hn);                                                    \
      hold[q] = b2f(hb);                                                              \
      HS2[WB][qrow + q][w * 16 + l15] = hb;                                           \
    }                                                                                 \
    __syncthreads();                                                                  \
  } while (0)

// ---------------- combined GRU chunk: rec blocks [0,NGRP) + GI-for-next blocks [NGRP, NGRP+136) ----------------
// rec: 16 waves, wave = 1 triple; wreg[3][6] from packed WhP + WL (packed kt 6,7) +
//      double-buffered HS (1 barrier/step); GI prefetched ONE STEP AHEAD (A/B named regs).
// gi:  136 consolidated blocks (4 t-slices each) overlapping on the CUs rec leaves free.
__global__ __launch_bounds__(1024, 4) void gru_combo(
    const unsigned short* __restrict__ GIcur, unsigned short* __restrict__ GInext,
    const unsigned short* __restrict__ Zb, const unsigned short* __restrict__ WiP,
    const unsigned short* __restrict__ WhP,
    const float* __restrict__ BA, const float* __restrict__ BB,
    unsigned short* __restrict__ Hst, int isFirst, int tbaseNext) {
  __shared__ unsigned short WL[96 * 512];     // Wh kt 6,7 frags: [tg*2+(kt-6)][lane][8], 96KB
  __shared__ unsigned short HS2[2][16][262];  // double-buffered h state

  const int tid = threadIdx.x;
  const int w = tid >> 6;            // 0..15  (= triple index)
  const int lane = tid & 63;
  const int l15 = lane & 15;
  const int lk = (lane >> 4) << 3;

  if (blockIdx.x >= NGRP) {
    // ---------- GI GEMM for next chunk: 136 blocks x 4 t-slices ----------
    int bid2 = blockIdx.x - NGRP;     // 0..135
    int pair = bid2 % 68, th = bid2 / 68;
#pragma unroll 1
    for (int tl = 0; tl < 4; ++tl) {
      int tloc = th * 4 + tl;
      int t = tbaseNext + tloc;
      bf16x8 a[2][4];
#pragma unroll
      for (int gl = 0; gl < 2; ++gl) {
        const unsigned short* zf = Zb + (((size_t)t * NGRP + pair * 2 + gl) * 4) * 512 + lane * 8;
#pragma unroll
        for (int kt = 0; kt < 4; ++kt) a[gl][kt] = *(const bf16x8*)(zf + kt * 512);
      }
      f32x4 acc[2][3];
#pragma unroll
      for (int g = 0; g < 3; ++g) {
        float b = BA[w * 48 + g * 16 + l15];
        f32x4 bv = {b, b, b, b};
        acc[0][g] = bv;
        acc[1][g] = bv;
      }
      int wW = w >> 1, ctb = (w & 1) * 3;
#pragma unroll
      for (int g = 0; g < 3; ++g) {
        const unsigned short* wf = WiP + ((size_t)((wW * 6 + ctb + g) * 4)) * 512 + lane * 8;
#pragma unroll
        for (int kt = 0; kt < 4; ++kt) {
          bf16x8 b = *(const bf16x8*)(wf + kt * 512);
          acc[0][g] = __builtin_amdgcn_mfma_f32_16x16x32_bf16(a[0][kt], b, acc[0][g], 0, 0, 0);
          acc[1][g] = __builtin_amdgcn_mfma_f32_16x16x32_bf16(a[1][kt], b, acc[1][g], 0, 0, 0);
        }
      }
#pragma unroll
      for (int gl = 0; gl < 2; ++gl) {
        unsigned short* gout = GInext + (((size_t)tloc * NGRP + pair * 2 + gl) * 48) * 256;
#pragma unroll
        for (int g = 0; g < 3; ++g) {
          unsigned short us[4];
#pragma unroll
          for (int q = 0; q < 4; ++q) us[q] = f2b(acc[gl][g][q]);
          *(uint2*)(gout + (size_t)(w * 3 + g) * 256 + lane * 4) = *(const uint2*)us;
        }
      }
    }
    return;
  }

  // ---------- recurrent h-part for current chunk ----------
  const int qrow = (lane >> 4) << 2;
  const int node0 = blockIdx.x * 16;

  // prologue GI load (step 0) issued FIRST — HBM latency hides under LDS staging
  const unsigned short* gblk = GIcur + ((size_t)blockIdx.x * 48 + w * 3) * 256 + lane * 4;
  const size_t tstep = (size_t)NGRP * 48 * 256;
  uint2 gAr = *(const uint2*)(gblk);
  uint2 gAz = *(const uint2*)(gblk + 256);
  uint2 gAn = *(const uint2*)(gblk + 512);
  uint2 gBr, gBz, gBn;

  // WL load: packed frags tg*8+{6,7} -> WL[tg*2+{0,1}]; fully coalesced, conflict-free
  for (int idx = tid; idx < 96 * 512; idx += 1024) {
    int fr = idx >> 9, e = idx & 511;
    int tg = fr >> 1, kt2 = fr & 1;
    WL[idx] = WhP[(size_t)(tg * 8 + 6 + kt2) * 512 + e];
  }
  if (isFirst) {
    for (int idx = tid; idx < 16 * 262; idx += 1024) ((unsigned short*)HS2[0])[idx] = 0;
  } else {
    for (int idx = tid; idx < 16 * 256; idx += 1024) {
      int r = idx >> 8, c = idx & 255;
      HS2[0][r][c] = Hst[(size_t)(node0 + r) * 256 + c];
    }
  }

  // persistent Wh regs from packed WhP: kt 0..5 (coalesced 1KB bursts)
  bf16x8 wreg[3][6];
#pragma unroll
  for (int g = 0; g < 3; ++g)
#pragma unroll
    for (int kt = 0; kt < 6; ++kt)
      wreg[g][kt] = *(const bf16x8*)(WhP + (size_t)((w * 3 + g) * 8 + kt) * 512 + lane * 8);

  const float bbn = BB[w * 48 + 32 + l15];

  float hold[4];
  if (isFirst) {
#pragma unroll
    for (int q = 0; q < 4; ++q) hold[q] = 0.f;
  } else {
#pragma unroll
    for (int q = 0; q < 4; ++q)
      hold[q] = b2f(Hst[(size_t)(node0 + qrow + q) * 256 + w * 16 + l15]);
  }

  __syncthreads();

#pragma unroll 1
  for (int tt = 0; tt < TCH / 2; ++tt) {
    int tinvv = 0;
    asm volatile("" : "+s"(tinvv));   // block LICM of t-invariant WL reads

    {  // prefetch GI for odd step (t = 2tt+1) — hides HBM latency under even step's MFMAs
      const unsigned short* gb = gblk + (size_t)(2 * tt + 1) * tstep;
      gBr = *(const uint2*)gb; gBz = *(const uint2*)(gb + 256); gBn = *(const uint2*)(gb + 512);
    }
    REC_STEP(gAr, gAz, gAn, 0, 1, tinvv);           // even step: read HS2[0], write HS2[1]
    {  // prefetch GI for next even step (clamped; redundant final load harmless)
      int tn = (2 * tt + 2 < TCH) ? 2 * tt + 2 : TCH - 1;
      const unsigned short* gb = gblk + (size_t)tn * tstep;
      gAr = *(const uint2*)gb; gAz = *(const uint2*)(gb + 256); gAn = *(const uint2*)(gb + 512);
    }
    REC_STEP(gBr, gBz, gBn, 1, 0, tinvv);           // odd step: read HS2[1], write HS2[0]
  }

  // h -> global
#pragma unroll
  for (int q = 0; q < 4; ++q)
    Hst[(size_t)(node0 + qrow + q) * 256 + w * 16 + l15] = f2b(hold[q]);
}

// ---------------- pooling (two-stage) + final projection ----------------
__global__ __launch_bounds__(256) void pool_part(const unsigned short* __restrict__ Hb,
                                                 float* __restrict__ part) {
  int blk = blockIdx.x;   // 0..135, 16 nodes each
  int j = threadIdx.x;
  int base = blk * 16;
  float s = 0.f;
  for (int r = 0; r < 16; ++r) s += b2f(Hb[(size_t)(base + r) * 256 + j]);
  part[blk * 256 + j] = s;
}

__global__ __launch_bounds__(256) void pool_final(const float* __restrict__ part,
                                                  float* __restrict__ pooled) {
  int typ = blockIdx.x;
  int j = threadIdx.x;
  int b0 = (typ == 0) ? 0 : (typ == 1 ? 64 : 128);
  int b1 = (typ == 2) ? 136 : b0 + 64;
  float s = 0.f;
  for (int b = b0; b < b1; ++b) s += part[b * 256 + j];
  pooled[typ * 256 + j] = s / (float)((typ == 2) ? 128 : 1024);
}

__global__ __launch_bounds__(128) void out_kernel(
    const float* __restrict__ pooled, const float* __restrict__ Wout,
    const float* __restrict__ bout, float* __restrict__ out) {
  int o = threadIdx.x;
  float acc = bout[o];
  for (int g = 0; g < GG; ++g) acc = fmaf(pooled[g], Wout[g * 128 + o], acc);
  out[o] = acc;
}

// ---------------- host launcher ----------------
extern "C" void kernel_launch(void* const* d_in, const int* in_sizes, int n_in,
                              void* d_out, int out_size, void* d_ws, size_t ws_size,
                              hipStream_t stream) {
  const float* xa    = (const float*)d_in[0];
  const float* xd    = (const float*)d_in[1];
  const float* xb    = (const float*)d_in[2];
  const int*   ei_aa = (const int*)d_in[3];
  const int*   ei_ad = (const int*)d_in[4];
  const int*   ei_dd = (const int*)d_in[5];
  const int*   ei_ab = (const int*)d_in[6];
  const int*   ei_db = (const int*)d_in[7];
  const float* Wp_a = (const float*)d_in[8];  const float* bp_a = (const float*)d_in[9];
  const float* Wp_d = (const float*)d_in[10]; const float* bp_d = (const float*)d_in[11];
  const float* Wp_b = (const float*)d_in[12]; const float* bp_b = (const float*)d_in[13];
  const float* Wg_aa = (const float*)d_in[14]; const float* bg_aa = (const float*)d_in[15];
  const float* Wg_dd = (const float*)d_in[16]; const float* bg_dd = (const float*)d_in[17];
  const float* Wl_ad = (const float*)d_in[18]; const float* Wr_ad = (const float*)d_in[19];
  const float* bl_ad = (const float*)d_in[20];
  const float* Wl_ab = (const float*)d_in[21]; const float* Wr_ab = (const float*)d_in[22];
  const float* bl_ab = (const float*)d_in[23];
  const float* Wl_db = (const float*)d_in[24]; const float* Wr_db = (const float*)d_in[25];
  const float* bl_db = (const float*)d_in[26];
  const float* Wi   = (const float*)d_in[27]; const float* Wh   = (const float*)d_in[28];
  const float* bi   = (const float*)d_in[29]; const float* bh   = (const float*)d_in[30];
  const float* Wout = (const float*)d_in[31]; const float* bout = (const float*)d_in[32];

  float* ws   = (float*)d_ws;
  unsigned short* Pb  = (unsigned short*)(ws + OFF_PB);
  unsigned short* Zb  = (unsigned short*)(ws + OFF_ZB);
  unsigned short* Hst = (unsigned short*)(ws + OFF_H0);
  float* BA = ws + OFF_BA;
  float* BB = ws + OFF_BB;
  unsigned short* WTgP = (unsigned short*)(ws + OFF_WTG);
  float* BT = ws + OFF_BT;
  unsigned short* WiP = (unsigned short*)(ws + OFF_WIP);
  unsigned short* WhP = (unsigned short*)(ws + OFF_WHP);
  float* pooled = ws + OFF_POOL;
  float* part   = ws + OFF_PART;
  int*   st  = (int*)(ws + OFF_STATS);
  unsigned short* GI0 = (unsigned short*)(ws + OFF_GI0);
  unsigned short* GI1 = (unsigned short*)(ws + OFF_GI1);

  hipMemsetAsync(st, 0, (size_t)S_ZERO_END * 4, stream);

  // --- CSR build (3 kernels) ---
  count_all<<<NEDGE / 256, 256, 0, stream>>>(ei_aa, ei_dd, ei_ad, ei_ab, ei_db, st);
  scan5<<<5, 1024, 0, stream>>>(st);
  fill_all<<<NEDGE / 256, 256, 0, stream>>>(ei_aa, ei_dd, ei_ad, ei_ab, ei_db, st);

  // --- projections + merged weight prep (packed layouts) ---
  proj64<<<TT * 34, 256, 0, stream>>>(xa, xd, xb, Wp_a, bp_a, Wp_d, bp_d, Wp_b, bp_b, Pb);
  prep_w<<<416, 512, 0, stream>>>(Wg_aa, Wg_dd, Wl_ad, Wr_ad, Wl_ab, Wl_db, Wr_ab, Wr_db,
                                  bg_aa, bg_dd, bl_ad, bl_ab, bl_db,
                                  Wi, Wh, bi, bh, WTgP, BT, WiP, WhP, BA, BB);

  // --- fused GNN: Pb -> Zb (frag-packed, XCD frame affinity, packed weights) ---
  gnn_fused<<<TT * 34, 512, 0, stream>>>(Pb, Zb, WTgP, BT, st);

  // --- GRU: 6 chunks; GI for chunk c+1 overlaps chunk c's recurrence ---
  gi_gemm<<<TCH * 68, 256, 0, stream>>>(Zb, WiP, BA, GI0, 0);
  for (int c = 0; c < 6; ++c) {
    unsigned short* gcur = (c & 1) ? GI1 : GI0;
    unsigned short* gnxt = (c & 1) ? GI0 : GI1;
    int grid = NGRP + ((c < 5) ? 136 : 0);
    gru_combo<<<grid, 1024, 0, stream>>>(gcur, gnxt, Zb, WiP, WhP, BA, BB,
                                         Hst, c == 0, (c + 1) * TCH);
  }

  // --- pool + output ---
  pool_part<<<NGRP, 256, 0, stream>>>(Hst, part);
  pool_final<<<3, 256, 0, stream>>>(part, pooled);
  out_kernel<<<1, 128, 0, stream>>>(pooled, Wout, bout, (float*)d_out);
}